// Round 1
// baseline (10059.243 us; speedup 1.0000x reference)
//
#include <hip/hip_runtime.h>
#include <math.h>

// ChebNet: 4 layers of ChebConv(K=3) + sigmoid.
// norm = -D^{-1/2} A D^{-1/2} (self loops removed)
// per layer: t1 = L@h ; t2 = 2*L@t1 - h ; out = sigmoid(h@W0 + t1@W1 + t2@W2 + b)

// ---------------- kernels ----------------

__global__ void deg_kernel(const int* __restrict__ row, const int* __restrict__ col,
                           const float* __restrict__ ew, float* __restrict__ deg, int E) {
    int e = blockIdx.x * 256 + threadIdx.x;
    if (e >= E) return;
    int r = row[e];
    float w = (r == col[e]) ? 0.0f : ew[e];
    if (w != 0.0f) atomicAdd(&deg[r], w);
}

__global__ void norm_kernel(const int* __restrict__ row, const int* __restrict__ col,
                            const float* __restrict__ ew, const float* __restrict__ deg,
                            float* __restrict__ nrm, int E) {
    int e = blockIdx.x * 256 + threadIdx.x;
    if (e >= E) return;
    int r = row[e], c = col[e];
    float w = (r == c) ? 0.0f : ew[e];
    float dr = deg[r], dc = deg[c];
    float ir = dr > 0.0f ? rsqrtf(dr) : 0.0f;
    float ic = dc > 0.0f ? rsqrtf(dc) : 0.0f;
    nrm[e] = -ir * w * ic;
}

// t2 = -h  (float4 vectorized)
__global__ void negcopy_kernel(const float4* __restrict__ src, float4* __restrict__ dst, long n4) {
    long i = (long)blockIdx.x * 256 + threadIdx.x;
    if (i >= n4) return;
    float4 v = src[i];
    dst[i] = make_float4(-v.x, -v.y, -v.z, -v.w);
}

// out[col] += (SCALE2 ? 2 : 1) * norm[e] * t[row]   (D floats per edge, D/4 lanes x float4)
template <int D, bool SCALE2>
__global__ void prop_kernel(const int* __restrict__ row, const int* __restrict__ col,
                            const float* __restrict__ nrm,
                            const float* __restrict__ t, float* __restrict__ out, int E) {
    constexpr int LPE = D / 4;  // lanes per edge
    long idx = (long)blockIdx.x * 256 + threadIdx.x;
    int e = (int)(idx / LPE);
    int l = (int)(idx % LPE);
    if (e >= E) return;
    float n = nrm[e];
    if (SCALE2) n *= 2.0f;
    if (n == 0.0f) return;
    int r = row[e], c = col[e];
    float4 v = *reinterpret_cast<const float4*>(t + (long)r * D + l * 4);
    float* o = out + (long)c * D + l * 4;
    atomicAdd(o + 0, n * v.x);
    atomicAdd(o + 1, n * v.y);
    atomicAdd(o + 2, n * v.z);
    atomicAdd(o + 3, n * v.w);
}

// out = sigmoid(t0@W[0] + t1@W[1] + t2@W[2] + b), W: (3, DIN, DOUT) row-major
template <int DIN, int DOUT>
__global__ void gemm3_kernel(const float* __restrict__ t0, const float* __restrict__ t1,
                             const float* __restrict__ t2, const float* __restrict__ W,
                             const float* __restrict__ b, float* __restrict__ out, int n) {
    __shared__ float sW[3 * DIN * DOUT];
    __shared__ float sb[DOUT];
    for (int i = threadIdx.x; i < 3 * DIN * DOUT; i += 256) sW[i] = W[i];
    if (threadIdx.x < DOUT) sb[threadIdx.x] = b[threadIdx.x];
    __syncthreads();
    constexpr int ROWS = 256 / DOUT;
    int oc = threadIdx.x % DOUT;
    int r = blockIdx.x * ROWS + threadIdx.x / DOUT;
    if (r >= n) return;
    const float* p0 = t0 + (long)r * DIN;
    const float* p1 = t1 + (long)r * DIN;
    const float* p2 = t2 + (long)r * DIN;
    float acc = sb[oc];
#pragma unroll
    for (int d = 0; d < DIN; ++d) {
        acc = fmaf(p0[d], sW[d * DOUT + oc], acc);
        acc = fmaf(p1[d], sW[(DIN + d) * DOUT + oc], acc);
        acc = fmaf(p2[d], sW[(2 * DIN + d) * DOUT + oc], acc);
    }
    out[(long)r * DOUT + oc] = 1.0f / (1.0f + expf(-acc));
}

// ---------------- host side ----------------

static inline int ceil_div_l(long a, long b) { return (int)((a + b - 1) / b); }

template <int DIN, int DOUT>
static void run_layer(const float* h, const float* W, const float* b,
                      float* t1, float* t2, float* out,
                      const int* row, const int* col, const float* nrm,
                      int n, int E, hipStream_t stream) {
    hipMemsetAsync(t1, 0, (size_t)n * DIN * sizeof(float), stream);
    long nth = (long)E * (DIN / 4);
    int pb = ceil_div_l(nth, 256);
    prop_kernel<DIN, false><<<pb, 256, 0, stream>>>(row, col, nrm, h, t1, E);
    long n4 = (long)n * DIN / 4;
    negcopy_kernel<<<ceil_div_l(n4, 256), 256, 0, stream>>>(
        (const float4*)h, (float4*)t2, n4);
    prop_kernel<DIN, true><<<pb, 256, 0, stream>>>(row, col, nrm, t1, t2, E);
    constexpr int ROWS = 256 / DOUT;
    gemm3_kernel<DIN, DOUT><<<ceil_div_l(n, ROWS), 256, 0, stream>>>(h, t1, t2, W, b, out, n);
}

extern "C" void kernel_launch(void* const* d_in, const int* in_sizes, int n_in,
                              void* d_out, int out_size, void* d_ws, size_t ws_size,
                              hipStream_t stream) {
    const float* x  = (const float*)d_in[0];
    const int*   ei = (const int*)d_in[1];
    const float* ew = (const float*)d_in[2];
    const float* W1 = (const float*)d_in[3];  const float* b1 = (const float*)d_in[4];
    const float* W2 = (const float*)d_in[5];  const float* b2 = (const float*)d_in[6];
    const float* W3 = (const float*)d_in[7];  const float* b3 = (const float*)d_in[8];
    const float* W4 = (const float*)d_in[9];  const float* b4 = (const float*)d_in[10];

    const int E = in_sizes[2];          // 1,600,000
    const int n = in_sizes[0] / 64;     // 100,000
    const int* row = ei;
    const int* col = ei + E;

    // workspace carve-up (256B aligned)
    char* ws = (char*)d_ws;
    size_t off = 0;
    auto alloc = [&](size_t bytes) -> void* {
        void* p = ws + off;
        off += (bytes + 255) & ~(size_t)255;
        return p;
    };
    float* deg  = (float*)alloc((size_t)n * sizeof(float));
    float* nrm  = (float*)alloc((size_t)E * sizeof(float));
    float* bufA = (float*)alloc((size_t)n * 64 * sizeof(float));
    float* bufB = (float*)alloc((size_t)n * 64 * sizeof(float));  // t1
    float* bufC = (float*)alloc((size_t)n * 64 * sizeof(float));  // t2
    float* bufD = (float*)alloc((size_t)n * 64 * sizeof(float));
    if (off > ws_size) return;  // fail loudly (validation) rather than corrupt

    // norm precompute
    hipMemsetAsync(deg, 0, (size_t)n * sizeof(float), stream);
    deg_kernel<<<ceil_div_l(E, 256), 256, 0, stream>>>(row, col, ew, deg, E);
    norm_kernel<<<ceil_div_l(E, 256), 256, 0, stream>>>(row, col, ew, deg, nrm, E);

    // 4 Chebyshev layers
    run_layer<64, 64>(x,    W1, b1, bufB, bufC, bufA, row, col, nrm, n, E, stream);
    run_layer<64, 64>(bufA, W2, b2, bufB, bufC, bufD, row, col, nrm, n, E, stream);
    run_layer<64, 32>(bufD, W3, b3, bufB, bufC, bufA, row, col, nrm, n, E, stream);
    run_layer<32, 16>(bufA, W4, b4, bufB, bufC, (float*)d_out, row, col, nrm, n, E, stream);
}

// Round 2
// 1277.999 us; speedup vs baseline: 7.8711x; 7.8711x over previous
//
#include <hip/hip_runtime.h>
#include <math.h>

// ChebNet: 4 layers of ChebConv(K=3) + sigmoid.
// norm = -D^{-1/2} A D^{-1/2} (self loops removed)
// per layer: t1 = L@h ; t2 = 2*L@t1 - h ; out = sigmoid(h@W0 + t1@W1 + t2@W2 + b)
//
// R1: replaced atomic scatter-add propagation (WRITE_SIZE 1.6 GB/prop, atomic-bound)
// with a per-call CSR build (hist+scan+permute) + gather aggregation per dest node
// (register accumulate, one coalesced non-atomic write per row).

// ---------------- norm ----------------

__global__ void deg_kernel(const int* __restrict__ row, const int* __restrict__ col,
                           const float* __restrict__ ew, float* __restrict__ deg, int E) {
    int e = blockIdx.x * 256 + threadIdx.x;
    if (e >= E) return;
    int r = row[e];
    float w = (r == col[e]) ? 0.0f : ew[e];
    if (w != 0.0f) atomicAdd(&deg[r], w);
}

__global__ void norm_kernel(const int* __restrict__ row, const int* __restrict__ col,
                            const float* __restrict__ ew, const float* __restrict__ deg,
                            float* __restrict__ nrm, int E) {
    int e = blockIdx.x * 256 + threadIdx.x;
    if (e >= E) return;
    int r = row[e], c = col[e];
    float w = (r == c) ? 0.0f : ew[e];
    float dr = deg[r], dc = deg[c];
    float ir = dr > 0.0f ? rsqrtf(dr) : 0.0f;
    float ic = dc > 0.0f ? rsqrtf(dc) : 0.0f;
    nrm[e] = -ir * w * ic;
}

// ---------------- CSR build (by destination col) ----------------

__global__ void hist_kernel(const int* __restrict__ col, int* __restrict__ cnt, int E) {
    int e = blockIdx.x * 256 + threadIdx.x;
    if (e >= E) return;
    atomicAdd(&cnt[col[e]], 1);
}

// 3-pass exclusive scan (n ~ 100k)
__global__ void scan1_kernel(const int* __restrict__ in, int* __restrict__ out,
                             int* __restrict__ bsum, int n) {
    __shared__ int sh[256];
    int i = blockIdx.x * 256 + threadIdx.x;
    int v = (i < n) ? in[i] : 0;
    sh[threadIdx.x] = v;
    __syncthreads();
    for (int o = 1; o < 256; o <<= 1) {
        int t = (threadIdx.x >= o) ? sh[threadIdx.x - o] : 0;
        __syncthreads();
        sh[threadIdx.x] += t;
        __syncthreads();
    }
    if (i < n) out[i] = sh[threadIdx.x] - v;  // exclusive
    if (threadIdx.x == 255) bsum[blockIdx.x] = sh[255];
}

__global__ void scan2_kernel(int* __restrict__ bsum, int nb) {
    __shared__ int sh[512];
    int v = (threadIdx.x < nb) ? bsum[threadIdx.x] : 0;
    sh[threadIdx.x] = v;
    __syncthreads();
    for (int o = 1; o < 512; o <<= 1) {
        int t = (threadIdx.x >= o) ? sh[threadIdx.x - o] : 0;
        __syncthreads();
        sh[threadIdx.x] += t;
        __syncthreads();
    }
    if (threadIdx.x < nb) bsum[threadIdx.x] = sh[threadIdx.x] - v;
}

__global__ void scan3_kernel(int* __restrict__ out, const int* __restrict__ bsum, int n, int E) {
    int i = blockIdx.x * 256 + threadIdx.x;
    if (i < n) out[i] += bsum[blockIdx.x];
    if (i == 0) out[n] = E;  // sentinel
}

__global__ void scatter_kernel(const int* __restrict__ row, const int* __restrict__ col,
                               const float* __restrict__ nrm, int* __restrict__ cursor,
                               int* __restrict__ srcv, float* __restrict__ valv, int E) {
    int e = blockIdx.x * 256 + threadIdx.x;
    if (e >= E) return;
    int c = col[e];
    int p = atomicAdd(&cursor[c], 1);
    srcv[p] = row[e];
    valv[p] = nrm[e];
}

// ---------------- aggregation: out[node] = (MODE? 2*agg - base : agg) ----------------
// agg[node] = sum_{k in [ofs[node],ofs[node+1])} valv[k] * t[srcv[k]]

template <int D, int MODE>
__global__ void agg_kernel(const int* __restrict__ ofs, const int* __restrict__ srcv,
                           const float* __restrict__ valv, const float* __restrict__ t,
                           const float* __restrict__ base, float* __restrict__ out, int n) {
    constexpr int LPN = D / 4;  // lanes per node (float4 each)
    int idx = blockIdx.x * 256 + threadIdx.x;
    int node = idx / LPN;
    int l = idx % LPN;
    if (node >= n) return;
    int beg = ofs[node], end = ofs[node + 1];
    float4 acc = make_float4(0.f, 0.f, 0.f, 0.f);
    for (int k = beg; k < end; ++k) {
        int s = srcv[k];       // broadcast within 16-lane group
        float v = valv[k];
        float4 tv = *reinterpret_cast<const float4*>(t + (long)s * D + l * 4);
        acc.x = fmaf(v, tv.x, acc.x);
        acc.y = fmaf(v, tv.y, acc.y);
        acc.z = fmaf(v, tv.z, acc.z);
        acc.w = fmaf(v, tv.w, acc.w);
    }
    long o = (long)node * D + l * 4;
    if (MODE == 1) {
        float4 bv = *reinterpret_cast<const float4*>(base + o);
        acc.x = 2.f * acc.x - bv.x;
        acc.y = 2.f * acc.y - bv.y;
        acc.z = 2.f * acc.z - bv.z;
        acc.w = 2.f * acc.w - bv.w;
    }
    *reinterpret_cast<float4*>(out + o) = acc;
}

// ---------------- fused 3-term GEMM + bias + sigmoid ----------------
// out = sigmoid(t0@W[0] + t1@W[1] + t2@W[2] + b), W: (3, DIN, DOUT) row-major

template <int DIN, int DOUT>
__global__ void gemm3_kernel(const float* __restrict__ t0, const float* __restrict__ t1,
                             const float* __restrict__ t2, const float* __restrict__ W,
                             const float* __restrict__ b, float* __restrict__ out, int n) {
    __shared__ float sW[3 * DIN * DOUT];
    __shared__ float sb[DOUT];
    for (int i = threadIdx.x; i < 3 * DIN * DOUT; i += 256) sW[i] = W[i];
    if (threadIdx.x < DOUT) sb[threadIdx.x] = b[threadIdx.x];
    __syncthreads();
    constexpr int ROWS = 256 / DOUT;
    int oc = threadIdx.x % DOUT;
    int r = blockIdx.x * ROWS + threadIdx.x / DOUT;
    if (r >= n) return;
    const float* p0 = t0 + (long)r * DIN;
    const float* p1 = t1 + (long)r * DIN;
    const float* p2 = t2 + (long)r * DIN;
    float acc = sb[oc];
#pragma unroll
    for (int d = 0; d < DIN; ++d) {
        acc = fmaf(p0[d], sW[d * DOUT + oc], acc);
        acc = fmaf(p1[d], sW[(DIN + d) * DOUT + oc], acc);
        acc = fmaf(p2[d], sW[(2 * DIN + d) * DOUT + oc], acc);
    }
    out[(long)r * DOUT + oc] = 1.0f / (1.0f + expf(-acc));
}

// ---------------- host side ----------------

static inline int ceil_div_l(long a, long b) { return (int)((a + b - 1) / b); }

template <int DIN, int DOUT>
static void run_layer(const float* h, const float* W, const float* b,
                      float* t1, float* t2, float* out,
                      const int* ofs, const int* srcv, const float* valv,
                      int n, hipStream_t stream) {
    constexpr int LPN = DIN / 4;
    int ab = ceil_div_l((long)n * LPN, 256);
    agg_kernel<DIN, 0><<<ab, 256, 0, stream>>>(ofs, srcv, valv, h, nullptr, t1, n);
    agg_kernel<DIN, 1><<<ab, 256, 0, stream>>>(ofs, srcv, valv, t1, h, t2, n);
    constexpr int ROWS = 256 / DOUT;
    gemm3_kernel<DIN, DOUT><<<ceil_div_l(n, ROWS), 256, 0, stream>>>(h, t1, t2, W, b, out, n);
}

extern "C" void kernel_launch(void* const* d_in, const int* in_sizes, int n_in,
                              void* d_out, int out_size, void* d_ws, size_t ws_size,
                              hipStream_t stream) {
    const float* x  = (const float*)d_in[0];
    const int*   ei = (const int*)d_in[1];
    const float* ew = (const float*)d_in[2];
    const float* W1 = (const float*)d_in[3];  const float* b1 = (const float*)d_in[4];
    const float* W2 = (const float*)d_in[5];  const float* b2 = (const float*)d_in[6];
    const float* W3 = (const float*)d_in[7];  const float* b3 = (const float*)d_in[8];
    const float* W4 = (const float*)d_in[9];  const float* b4 = (const float*)d_in[10];

    const int E = in_sizes[2];          // 1,600,000
    const int n = in_sizes[0] / 64;     // 100,000
    const int* row = ei;
    const int* col = ei + E;

    // workspace carve-up (256B aligned)
    char* ws = (char*)d_ws;
    size_t off = 0;
    auto alloc = [&](size_t bytes) -> void* {
        void* p = ws + off;
        off += (bytes + 255) & ~(size_t)255;
        return p;
    };
    float* deg    = (float*)alloc((size_t)n * sizeof(float));
    float* nrm    = (float*)alloc((size_t)E * sizeof(float));
    int*   cnt    = (int*)alloc((size_t)n * sizeof(int));
    int*   ofs    = (int*)alloc((size_t)(n + 1) * sizeof(int));
    int*   cursor = (int*)alloc((size_t)n * sizeof(int));
    int*   bsum   = (int*)alloc(512 * sizeof(int));
    int*   srcv   = (int*)alloc((size_t)E * sizeof(int));
    float* valv   = (float*)alloc((size_t)E * sizeof(float));
    float* bufA   = (float*)alloc((size_t)n * 64 * sizeof(float));
    float* bufB   = (float*)alloc((size_t)n * 64 * sizeof(float));  // t1
    float* bufC   = (float*)alloc((size_t)n * 64 * sizeof(float));  // t2
    float* bufD   = (float*)alloc((size_t)n * 64 * sizeof(float));
    if (off > ws_size) return;  // fail loudly (validation) rather than corrupt

    int eb = ceil_div_l(E, 256);
    int nb = ceil_div_l(n, 256);  // 391 <= 512

    // norm precompute
    hipMemsetAsync(deg, 0, (size_t)n * sizeof(float), stream);
    deg_kernel<<<eb, 256, 0, stream>>>(row, col, ew, deg, E);
    norm_kernel<<<eb, 256, 0, stream>>>(row, col, ew, deg, nrm, E);

    // CSR build keyed by destination (col)
    hipMemsetAsync(cnt, 0, (size_t)n * sizeof(int), stream);
    hist_kernel<<<eb, 256, 0, stream>>>(col, cnt, E);
    scan1_kernel<<<nb, 256, 0, stream>>>(cnt, ofs, bsum, n);
    scan2_kernel<<<1, 512, 0, stream>>>(bsum, nb);
    scan3_kernel<<<nb, 256, 0, stream>>>(ofs, bsum, n, E);
    hipMemcpyAsync(cursor, ofs, (size_t)n * sizeof(int), hipMemcpyDeviceToDevice, stream);
    scatter_kernel<<<eb, 256, 0, stream>>>(row, col, nrm, cursor, srcv, valv, E);

    // 4 Chebyshev layers
    run_layer<64, 64>(x,    W1, b1, bufB, bufC, bufA, ofs, srcv, valv, n, stream);
    run_layer<64, 64>(bufA, W2, b2, bufB, bufC, bufD, ofs, srcv, valv, n, stream);
    run_layer<64, 32>(bufD, W3, b3, bufB, bufC, bufA, ofs, srcv, valv, n, stream);
    run_layer<32, 16>(bufA, W4, b4, bufB, bufC, (float*)d_out, ofs, srcv, valv, n, stream);
}

// Round 3
// 949.406 us; speedup vs baseline: 10.5953x; 1.3461x over previous
//
#include <hip/hip_runtime.h>
#include <math.h>

// ChebNet: 4 layers of ChebConv(K=3) + sigmoid.
// norm = -D^{-1/2} A D^{-1/2} (self loops removed)
// per layer: t1 = L@h ; t2 = 2*L@t1 - h ; out = sigmoid(h@W0 + t1@W1 + t2@W2 + b)
//
// R1: atomic scatter -> CSR (dest-sorted) gather; 10.06ms -> 1.28ms
// R2: register-tiled gemm3 (4 rows x 8 cols/thread, float4 LDS weights),
//     agg with 8-float lanes + 2-edge unroll, fused CSR build.

// ---------------- fused degree + histogram ----------------

__global__ __launch_bounds__(256) void deg_hist_kernel(
        const int* __restrict__ row, const int* __restrict__ col,
        const float* __restrict__ ew, float* __restrict__ deg,
        int* __restrict__ cnt, int E) {
    int e = blockIdx.x * 256 + threadIdx.x;
    if (e >= E) return;
    int r = row[e], c = col[e];
    float w = (r == c) ? 0.0f : ew[e];
    if (w != 0.0f) atomicAdd(&deg[r], w);
    atomicAdd(&cnt[c], 1);
}

// ---------------- scan (3-pass, n ~ 100k) ----------------

__global__ __launch_bounds__(256) void scan1_kernel(
        const int* __restrict__ in, int* __restrict__ out, int* __restrict__ bsum, int n) {
    __shared__ int sh[256];
    int i = blockIdx.x * 256 + threadIdx.x;
    int v = (i < n) ? in[i] : 0;
    sh[threadIdx.x] = v;
    __syncthreads();
    for (int o = 1; o < 256; o <<= 1) {
        int t = (threadIdx.x >= o) ? sh[threadIdx.x - o] : 0;
        __syncthreads();
        sh[threadIdx.x] += t;
        __syncthreads();
    }
    if (i < n) out[i] = sh[threadIdx.x] - v;  // exclusive
    if (threadIdx.x == 255) bsum[blockIdx.x] = sh[255];
}

__global__ __launch_bounds__(512) void scan2_kernel(int* __restrict__ bsum, int nb) {
    __shared__ int sh[512];
    int v = (threadIdx.x < nb) ? bsum[threadIdx.x] : 0;
    sh[threadIdx.x] = v;
    __syncthreads();
    for (int o = 1; o < 512; o <<= 1) {
        int t = (threadIdx.x >= o) ? sh[threadIdx.x - o] : 0;
        __syncthreads();
        sh[threadIdx.x] += t;
        __syncthreads();
    }
    if (threadIdx.x < nb) bsum[threadIdx.x] = sh[threadIdx.x] - v;
}

__global__ __launch_bounds__(256) void scan3_kernel(
        int* __restrict__ out, const int* __restrict__ bsum, int n, int E) {
    int i = blockIdx.x * 256 + threadIdx.x;
    if (i < n) out[i] += bsum[blockIdx.x];
    if (i == 0) out[n] = E;  // sentinel
}

// ---------------- scatter with inline norm ----------------

__global__ __launch_bounds__(256) void scatter_kernel(
        const int* __restrict__ row, const int* __restrict__ col,
        const float* __restrict__ ew, const float* __restrict__ deg,
        int* __restrict__ cursor, int* __restrict__ srcv, float* __restrict__ valv, int E) {
    int e = blockIdx.x * 256 + threadIdx.x;
    if (e >= E) return;
    int r = row[e], c = col[e];
    float w = (r == c) ? 0.0f : ew[e];
    float dr = deg[r], dc = deg[c];
    float ir = dr > 0.0f ? rsqrtf(dr) : 0.0f;
    float ic = dc > 0.0f ? rsqrtf(dc) : 0.0f;
    int p = atomicAdd(&cursor[c], 1);
    srcv[p] = r;
    valv[p] = -ir * w * ic;
}

// ---------------- aggregation ----------------
// out[node] = (MODE ? 2*agg - base : agg); agg = sum_k valv[k] * t[srcv[k]]
// LPN lanes per node; each lane owns cols [l*4, l*4+4) and [D/2 + l*4, ...+4)
// so every group load instruction is a fully-coalesced contiguous chunk.

template <int D, int MODE>
__global__ __launch_bounds__(256) void agg_kernel(
        const int* __restrict__ ofs, const int* __restrict__ srcv,
        const float* __restrict__ valv, const float* __restrict__ t,
        const float* __restrict__ base, float* __restrict__ out, int n) {
    constexpr int LPN = D / 8;  // 8 floats per lane
    int idx = blockIdx.x * 256 + threadIdx.x;
    int node = idx / LPN;
    int l = idx % LPN;
    if (node >= n) return;
    const int c0 = l * 4;
    const int c1 = D / 2 + l * 4;
    int beg = ofs[node], end = ofs[node + 1];
    float4 a0 = make_float4(0.f, 0.f, 0.f, 0.f);
    float4 a1 = make_float4(0.f, 0.f, 0.f, 0.f);
    int k = beg;
    for (; k + 2 <= end; k += 2) {
        int s0 = srcv[k], s1 = srcv[k + 1];
        float v0 = valv[k], v1 = valv[k + 1];
        const float* p0 = t + (long)s0 * D;
        const float* p1 = t + (long)s1 * D;
        float4 x0 = *reinterpret_cast<const float4*>(p0 + c0);
        float4 y0 = *reinterpret_cast<const float4*>(p0 + c1);
        float4 x1 = *reinterpret_cast<const float4*>(p1 + c0);
        float4 y1 = *reinterpret_cast<const float4*>(p1 + c1);
        a0.x = fmaf(v0, x0.x, a0.x); a0.y = fmaf(v0, x0.y, a0.y);
        a0.z = fmaf(v0, x0.z, a0.z); a0.w = fmaf(v0, x0.w, a0.w);
        a1.x = fmaf(v0, y0.x, a1.x); a1.y = fmaf(v0, y0.y, a1.y);
        a1.z = fmaf(v0, y0.z, a1.z); a1.w = fmaf(v0, y0.w, a1.w);
        a0.x = fmaf(v1, x1.x, a0.x); a0.y = fmaf(v1, x1.y, a0.y);
        a0.z = fmaf(v1, x1.z, a0.z); a0.w = fmaf(v1, x1.w, a0.w);
        a1.x = fmaf(v1, y1.x, a1.x); a1.y = fmaf(v1, y1.y, a1.y);
        a1.z = fmaf(v1, y1.z, a1.z); a1.w = fmaf(v1, y1.w, a1.w);
    }
    if (k < end) {
        int s0 = srcv[k];
        float v0 = valv[k];
        const float* p0 = t + (long)s0 * D;
        float4 x0 = *reinterpret_cast<const float4*>(p0 + c0);
        float4 y0 = *reinterpret_cast<const float4*>(p0 + c1);
        a0.x = fmaf(v0, x0.x, a0.x); a0.y = fmaf(v0, x0.y, a0.y);
        a0.z = fmaf(v0, x0.z, a0.z); a0.w = fmaf(v0, x0.w, a0.w);
        a1.x = fmaf(v0, y0.x, a1.x); a1.y = fmaf(v0, y0.y, a1.y);
        a1.z = fmaf(v0, y0.z, a1.z); a1.w = fmaf(v0, y0.w, a1.w);
    }
    long o = (long)node * D;
    if (MODE == 1) {
        float4 b0 = *reinterpret_cast<const float4*>(base + o + c0);
        float4 b1 = *reinterpret_cast<const float4*>(base + o + c1);
        a0.x = 2.f * a0.x - b0.x; a0.y = 2.f * a0.y - b0.y;
        a0.z = 2.f * a0.z - b0.z; a0.w = 2.f * a0.w - b0.w;
        a1.x = 2.f * a1.x - b1.x; a1.y = 2.f * a1.y - b1.y;
        a1.z = 2.f * a1.z - b1.z; a1.w = 2.f * a1.w - b1.w;
    }
    *reinterpret_cast<float4*>(out + o + c0) = a0;
    *reinterpret_cast<float4*>(out + o + c1) = a1;
}

// ---------------- fused 3-term GEMM + bias + sigmoid ----------------
// out = sigmoid(t0@W[0] + t1@W[1] + t2@W[2] + b), W: (3, DIN, DOUT) row-major
// Register tile: RPT=4 rows x CPT=8 cols per thread.

template <int DIN, int DOUT>
__global__ __launch_bounds__(256) void gemm3_kernel(
        const float* __restrict__ t0, const float* __restrict__ t1,
        const float* __restrict__ t2, const float* __restrict__ W,
        const float* __restrict__ b, float* __restrict__ out, int n) {
    constexpr int CPT = 8;
    constexpr int RPT = 4;
    constexpr int TPR = DOUT / CPT;   // threads per row: 8/4/2
    constexpr int TROWS = 256 / TPR;  // thread-rows per block
    constexpr int RPB = TROWS * RPT;  // rows per block

    __shared__ float sW[3 * DIN * DOUT];
    __shared__ float sb[DOUT];
    for (int i = threadIdx.x; i < 3 * DIN * DOUT; i += 256) sW[i] = W[i];
    if (threadIdx.x < DOUT) sb[threadIdx.x] = b[threadIdx.x];
    __syncthreads();

    const int oc = (threadIdx.x % TPR) * CPT;
    const int rt = threadIdx.x / TPR;
    const int rbase = blockIdx.x * RPB + rt;

    int rows[RPT];
#pragma unroll
    for (int i = 0; i < RPT; ++i) {
        int r = rbase + i * TROWS;
        rows[i] = (r < n) ? r : (n - 1);  // clamp loads, guard stores
    }

    float acc[RPT][CPT];
#pragma unroll
    for (int i = 0; i < RPT; ++i)
#pragma unroll
        for (int j = 0; j < CPT; ++j) acc[i][j] = 0.0f;

    const float* tp[3] = {t0, t1, t2};

    for (int d4 = 0; d4 < DIN; d4 += 4) {
        float4 av[3][RPT];
#pragma unroll
        for (int tt = 0; tt < 3; ++tt)
#pragma unroll
            for (int i = 0; i < RPT; ++i)
                av[tt][i] = *reinterpret_cast<const float4*>(tp[tt] + (long)rows[i] * DIN + d4);
#pragma unroll
        for (int dd = 0; dd < 4; ++dd) {
            int d = d4 + dd;
            float4 w[3][2];
#pragma unroll
            for (int tt = 0; tt < 3; ++tt) {
                const float4* wp = reinterpret_cast<const float4*>(sW + (tt * DIN + d) * DOUT + oc);
                w[tt][0] = wp[0];
                w[tt][1] = wp[1];
            }
#pragma unroll
            for (int tt = 0; tt < 3; ++tt) {
                const float* wf = reinterpret_cast<const float*>(&w[tt][0]);
#pragma unroll
                for (int i = 0; i < RPT; ++i) {
                    float a = reinterpret_cast<const float*>(&av[tt][i])[dd];
#pragma unroll
                    for (int j = 0; j < CPT; ++j)
                        acc[i][j] = fmaf(a, wf[j], acc[i][j]);
                }
            }
        }
    }

#pragma unroll
    for (int i = 0; i < RPT; ++i) {
        int r = rbase + i * TROWS;
        if (r >= n) continue;
        float res[CPT];
#pragma unroll
        for (int j = 0; j < CPT; ++j) {
            float z = acc[i][j] + sb[oc + j];
            res[j] = 1.0f / (1.0f + expf(-z));
        }
        float4* po = reinterpret_cast<float4*>(out + (long)r * DOUT + oc);
        po[0] = make_float4(res[0], res[1], res[2], res[3]);
        po[1] = make_float4(res[4], res[5], res[6], res[7]);
    }
}

// ---------------- host side ----------------

static inline int ceil_div_l(long a, long b) { return (int)((a + b - 1) / b); }

template <int DIN, int DOUT>
static void run_layer(const float* h, const float* W, const float* b,
                      float* t1, float* t2, float* out,
                      const int* ofs, const int* srcv, const float* valv,
                      int n, hipStream_t stream) {
    constexpr int LPN = DIN / 8;
    int ab = ceil_div_l((long)n * LPN, 256);
    agg_kernel<DIN, 0><<<ab, 256, 0, stream>>>(ofs, srcv, valv, h, nullptr, t1, n);
    agg_kernel<DIN, 1><<<ab, 256, 0, stream>>>(ofs, srcv, valv, t1, h, t2, n);
    constexpr int RPB = (256 / (DOUT / 8)) * 4;
    gemm3_kernel<DIN, DOUT><<<ceil_div_l(n, RPB), 256, 0, stream>>>(h, t1, t2, W, b, out, n);
}

extern "C" void kernel_launch(void* const* d_in, const int* in_sizes, int n_in,
                              void* d_out, int out_size, void* d_ws, size_t ws_size,
                              hipStream_t stream) {
    const float* x  = (const float*)d_in[0];
    const int*   ei = (const int*)d_in[1];
    const float* ew = (const float*)d_in[2];
    const float* W1 = (const float*)d_in[3];  const float* b1 = (const float*)d_in[4];
    const float* W2 = (const float*)d_in[5];  const float* b2 = (const float*)d_in[6];
    const float* W3 = (const float*)d_in[7];  const float* b3 = (const float*)d_in[8];
    const float* W4 = (const float*)d_in[9];  const float* b4 = (const float*)d_in[10];

    const int E = in_sizes[2];          // 1,600,000
    const int n = in_sizes[0] / 64;     // 100,000
    const int* row = ei;
    const int* col = ei + E;

    // workspace carve-up (256B aligned)
    char* ws = (char*)d_ws;
    size_t off = 0;
    auto alloc = [&](size_t bytes) -> void* {
        void* p = ws + off;
        off += (bytes + 255) & ~(size_t)255;
        return p;
    };
    float* deg    = (float*)alloc((size_t)n * sizeof(float));
    int*   cnt    = (int*)alloc((size_t)n * sizeof(int));
    int*   ofs    = (int*)alloc((size_t)(n + 1) * sizeof(int));
    int*   cursor = (int*)alloc((size_t)n * sizeof(int));
    int*   bsum   = (int*)alloc(512 * sizeof(int));
    int*   srcv   = (int*)alloc((size_t)E * sizeof(int));
    float* valv   = (float*)alloc((size_t)E * sizeof(float));
    float* bufA   = (float*)alloc((size_t)n * 64 * sizeof(float));
    float* bufB   = (float*)alloc((size_t)n * 64 * sizeof(float));  // t1
    float* bufC   = (float*)alloc((size_t)n * 64 * sizeof(float));  // t2
    float* bufD   = (float*)alloc((size_t)n * 64 * sizeof(float));
    if (off > ws_size) return;  // fail loudly (validation) rather than corrupt

    int eb = ceil_div_l(E, 256);
    int nb = ceil_div_l(n, 256);  // 391 <= 512

    // fused norm-degree + dest histogram
    hipMemsetAsync(deg, 0, (size_t)n * sizeof(float), stream);
    hipMemsetAsync(cnt, 0, (size_t)n * sizeof(int), stream);
    deg_hist_kernel<<<eb, 256, 0, stream>>>(row, col, ew, deg, cnt, E);

    // CSR offsets
    scan1_kernel<<<nb, 256, 0, stream>>>(cnt, ofs, bsum, n);
    scan2_kernel<<<1, 512, 0, stream>>>(bsum, nb);
    scan3_kernel<<<nb, 256, 0, stream>>>(ofs, bsum, n, E);
    hipMemcpyAsync(cursor, ofs, (size_t)n * sizeof(int), hipMemcpyDeviceToDevice, stream);
    scatter_kernel<<<eb, 256, 0, stream>>>(row, col, ew, deg, cursor, srcv, valv, E);

    // 4 Chebyshev layers
    run_layer<64, 64>(x,    W1, b1, bufB, bufC, bufA, ofs, srcv, valv, n, stream);
    run_layer<64, 64>(bufA, W2, b2, bufB, bufC, bufD, ofs, srcv, valv, n, stream);
    run_layer<64, 32>(bufD, W3, b3, bufB, bufC, bufA, ofs, srcv, valv, n, stream);
    run_layer<32, 16>(bufA, W4, b4, bufB, bufC, (float*)d_out, ofs, srcv, valv, n, stream);
}

// Round 4
// 823.001 us; speedup vs baseline: 12.2226x; 1.1536x over previous
//
#include <hip/hip_runtime.h>
#include <math.h>

// ChebNet: 4 layers of ChebConv(K=3) + sigmoid.
// norm = -D^{-1/2} A D^{-1/2} (self loops removed)
// per layer: t1 = L@h ; t2 = 2*L@t1 - h ; out = sigmoid(h@W0 + t1@W1 + t2@W2 + b)
//
// R1: atomic scatter -> CSR (dest-sorted) gather; 10.06ms -> 1.28ms
// R2: register-tiled gemm3, 8-float agg lanes, fused CSR build; 1.28 -> 0.949ms
// R3: packed (src,val) int2 edges, 4-edge-unrolled agg (deeper MLP),
//     scan3 writes cursor (drop memcpy), layer-3 commute form:
//     out = sigma(h@(W0-W2) + b + L@(h@W1) + 2*L@(L@(h@W2))) -- props in 32-dim.

__device__ __forceinline__ void fma4(float4& a, float v, const float4& x) {
    a.x = fmaf(v, x.x, a.x); a.y = fmaf(v, x.y, a.y);
    a.z = fmaf(v, x.z, a.z); a.w = fmaf(v, x.w, a.w);
}

// ---------------- fused degree + histogram ----------------

__global__ __launch_bounds__(256) void deg_hist_kernel(
        const int* __restrict__ row, const int* __restrict__ col,
        const float* __restrict__ ew, float* __restrict__ deg,
        int* __restrict__ cnt, int E) {
    int e = blockIdx.x * 256 + threadIdx.x;
    if (e >= E) return;
    int r = row[e], c = col[e];
    float w = (r == c) ? 0.0f : ew[e];
    if (w != 0.0f) atomicAdd(&deg[r], w);
    atomicAdd(&cnt[c], 1);
}

// ---------------- scan (3-pass, n ~ 100k) ----------------

__global__ __launch_bounds__(256) void scan1_kernel(
        const int* __restrict__ in, int* __restrict__ out, int* __restrict__ bsum, int n) {
    __shared__ int sh[256];
    int i = blockIdx.x * 256 + threadIdx.x;
    int v = (i < n) ? in[i] : 0;
    sh[threadIdx.x] = v;
    __syncthreads();
    for (int o = 1; o < 256; o <<= 1) {
        int t = (threadIdx.x >= o) ? sh[threadIdx.x - o] : 0;
        __syncthreads();
        sh[threadIdx.x] += t;
        __syncthreads();
    }
    if (i < n) out[i] = sh[threadIdx.x] - v;  // exclusive
    if (threadIdx.x == 255) bsum[blockIdx.x] = sh[255];
}

__global__ __launch_bounds__(512) void scan2_kernel(int* __restrict__ bsum, int nb) {
    __shared__ int sh[512];
    int v = (threadIdx.x < nb) ? bsum[threadIdx.x] : 0;
    sh[threadIdx.x] = v;
    __syncthreads();
    for (int o = 1; o < 512; o <<= 1) {
        int t = (threadIdx.x >= o) ? sh[threadIdx.x - o] : 0;
        __syncthreads();
        sh[threadIdx.x] += t;
        __syncthreads();
    }
    if (threadIdx.x < nb) bsum[threadIdx.x] = sh[threadIdx.x] - v;
}

__global__ __launch_bounds__(256) void scan3_kernel(
        int* __restrict__ ofs, int* __restrict__ cursor,
        const int* __restrict__ bsum, int n, int E) {
    int i = blockIdx.x * 256 + threadIdx.x;
    if (i < n) {
        int v = ofs[i] + bsum[blockIdx.x];
        ofs[i] = v;
        cursor[i] = v;
    }
    if (i == 0) ofs[n] = E;  // sentinel
}

// ---------------- scatter with inline norm, packed (src, val) ----------------

__global__ __launch_bounds__(256) void scatter_kernel(
        const int* __restrict__ row, const int* __restrict__ col,
        const float* __restrict__ ew, const float* __restrict__ deg,
        int* __restrict__ cursor, int2* __restrict__ epk, int E) {
    int e = blockIdx.x * 256 + threadIdx.x;
    if (e >= E) return;
    int r = row[e], c = col[e];
    float w = (r == c) ? 0.0f : ew[e];
    float dr = deg[r], dc = deg[c];
    float ir = dr > 0.0f ? rsqrtf(dr) : 0.0f;
    float ic = dc > 0.0f ? rsqrtf(dc) : 0.0f;
    int p = atomicAdd(&cursor[c], 1);
    epk[p] = make_int2(r, __float_as_int(-ir * w * ic));
}

// ---------------- aggregation ----------------
// out[node] = (MODE ? 2*agg - base : agg); agg = sum_k val[k] * t[src[k]]
// LPN = D/8 lanes per node, each lane owns cols [l*4,l*4+4) and [D/2+l*4,...).
// 4-edge unroll: all 8 gather float4s issued before the FMA block (MLP).

template <int D, int MODE>
__global__ __launch_bounds__(256) void agg_kernel(
        const int* __restrict__ ofs, const int2* __restrict__ epk,
        const float* __restrict__ t, const float* __restrict__ base,
        float* __restrict__ out, int n) {
    constexpr int LPN = D / 8;
    int idx = blockIdx.x * 256 + threadIdx.x;
    int node = idx / LPN;
    int l = idx % LPN;
    if (node >= n) return;
    const int c0 = l * 4;
    const int c1 = D / 2 + l * 4;
    int beg = ofs[node], end = ofs[node + 1];
    float4 a0 = make_float4(0.f, 0.f, 0.f, 0.f);
    float4 a1 = make_float4(0.f, 0.f, 0.f, 0.f);
    int k = beg;
    for (; k + 4 <= end; k += 4) {
        int2 e0 = epk[k], e1 = epk[k + 1], e2 = epk[k + 2], e3 = epk[k + 3];
        const float* p0 = t + (long)e0.x * D;
        const float* p1 = t + (long)e1.x * D;
        const float* p2 = t + (long)e2.x * D;
        const float* p3 = t + (long)e3.x * D;
        float4 x0 = *reinterpret_cast<const float4*>(p0 + c0);
        float4 y0 = *reinterpret_cast<const float4*>(p0 + c1);
        float4 x1 = *reinterpret_cast<const float4*>(p1 + c0);
        float4 y1 = *reinterpret_cast<const float4*>(p1 + c1);
        float4 x2 = *reinterpret_cast<const float4*>(p2 + c0);
        float4 y2 = *reinterpret_cast<const float4*>(p2 + c1);
        float4 x3 = *reinterpret_cast<const float4*>(p3 + c0);
        float4 y3 = *reinterpret_cast<const float4*>(p3 + c1);
        float v0 = __int_as_float(e0.y), v1 = __int_as_float(e1.y);
        float v2 = __int_as_float(e2.y), v3 = __int_as_float(e3.y);
        fma4(a0, v0, x0); fma4(a1, v0, y0);
        fma4(a0, v1, x1); fma4(a1, v1, y1);
        fma4(a0, v2, x2); fma4(a1, v2, y2);
        fma4(a0, v3, x3); fma4(a1, v3, y3);
    }
    for (; k < end; ++k) {
        int2 e0 = epk[k];
        const float* p0 = t + (long)e0.x * D;
        float4 x0 = *reinterpret_cast<const float4*>(p0 + c0);
        float4 y0 = *reinterpret_cast<const float4*>(p0 + c1);
        float v0 = __int_as_float(e0.y);
        fma4(a0, v0, x0); fma4(a1, v0, y0);
    }
    long o = (long)node * D;
    if (MODE == 1) {
        float4 b0 = *reinterpret_cast<const float4*>(base + o + c0);
        float4 b1 = *reinterpret_cast<const float4*>(base + o + c1);
        a0.x = 2.f * a0.x - b0.x; a0.y = 2.f * a0.y - b0.y;
        a0.z = 2.f * a0.z - b0.z; a0.w = 2.f * a0.w - b0.w;
        a1.x = 2.f * a1.x - b1.x; a1.y = 2.f * a1.y - b1.y;
        a1.z = 2.f * a1.z - b1.z; a1.w = 2.f * a1.w - b1.w;
    }
    *reinterpret_cast<float4*>(out + o + c0) = a0;
    *reinterpret_cast<float4*>(out + o + c1) = a1;
}

// ---------------- fused 3-term GEMM + bias + sigmoid ----------------

template <int DIN, int DOUT>
__global__ __launch_bounds__(256) void gemm3_kernel(
        const float* __restrict__ t0, const float* __restrict__ t1,
        const float* __restrict__ t2, const float* __restrict__ W,
        const float* __restrict__ b, float* __restrict__ out, int n) {
    constexpr int CPT = 8;
    constexpr int RPT = 4;
    constexpr int TPR = DOUT / CPT;
    constexpr int TROWS = 256 / TPR;
    constexpr int RPB = TROWS * RPT;

    __shared__ float sW[3 * DIN * DOUT];
    __shared__ float sb[DOUT];
    for (int i = threadIdx.x; i < 3 * DIN * DOUT; i += 256) sW[i] = W[i];
    if (threadIdx.x < DOUT) sb[threadIdx.x] = b[threadIdx.x];
    __syncthreads();

    const int oc = (threadIdx.x % TPR) * CPT;
    const int rt = threadIdx.x / TPR;
    const int rbase = blockIdx.x * RPB + rt;

    int rows[RPT];
#pragma unroll
    for (int i = 0; i < RPT; ++i) {
        int r = rbase + i * TROWS;
        rows[i] = (r < n) ? r : (n - 1);
    }

    float acc[RPT][CPT];
#pragma unroll
    for (int i = 0; i < RPT; ++i)
#pragma unroll
        for (int j = 0; j < CPT; ++j) acc[i][j] = 0.0f;

    const float* tp[3] = {t0, t1, t2};

    for (int d4 = 0; d4 < DIN; d4 += 4) {
        float4 av[3][RPT];
#pragma unroll
        for (int tt = 0; tt < 3; ++tt)
#pragma unroll
            for (int i = 0; i < RPT; ++i)
                av[tt][i] = *reinterpret_cast<const float4*>(tp[tt] + (long)rows[i] * DIN + d4);
#pragma unroll
        for (int dd = 0; dd < 4; ++dd) {
            int d = d4 + dd;
            float4 w[3][2];
#pragma unroll
            for (int tt = 0; tt < 3; ++tt) {
                const float4* wp = reinterpret_cast<const float4*>(sW + (tt * DIN + d) * DOUT + oc);
                w[tt][0] = wp[0];
                w[tt][1] = wp[1];
            }
#pragma unroll
            for (int tt = 0; tt < 3; ++tt) {
                const float* wf = reinterpret_cast<const float*>(&w[tt][0]);
#pragma unroll
                for (int i = 0; i < RPT; ++i) {
                    float a = reinterpret_cast<const float*>(&av[tt][i])[dd];
#pragma unroll
                    for (int j = 0; j < CPT; ++j)
                        acc[i][j] = fmaf(a, wf[j], acc[i][j]);
                }
            }
        }
    }

#pragma unroll
    for (int i = 0; i < RPT; ++i) {
        int r = rbase + i * TROWS;
        if (r >= n) continue;
        float res[CPT];
#pragma unroll
        for (int j = 0; j < CPT; ++j) {
            float z = acc[i][j] + sb[oc + j];
            res[j] = 1.0f / (1.0f + expf(-z));
        }
        float4* po = reinterpret_cast<float4*>(out + (long)r * DOUT + oc);
        po[0] = make_float4(res[0], res[1], res[2], res[3]);
        po[1] = make_float4(res[4], res[5], res[6], res[7]);
    }
}

// ---------------- multi-output GEMM for commute-form layer ----------------
// P1 = h@W[1], P2 = h@W[2], S = h@W[0] - P2 + b

template <int DIN, int DOUT>
__global__ __launch_bounds__(256) void gemm_multi_kernel(
        const float* __restrict__ h, const float* __restrict__ W,
        const float* __restrict__ b, float* __restrict__ P1,
        float* __restrict__ P2, float* __restrict__ S, int n) {
    constexpr int CPT = 8;
    constexpr int RPT = 2;
    constexpr int TPR = DOUT / CPT;   // 4 for DOUT=32
    constexpr int TROWS = 256 / TPR;  // 64
    constexpr int RPB = TROWS * RPT;  // 128

    __shared__ float sW[3 * DIN * DOUT];
    __shared__ float sb[DOUT];
    for (int i = threadIdx.x; i < 3 * DIN * DOUT; i += 256) sW[i] = W[i];
    if (threadIdx.x < DOUT) sb[threadIdx.x] = b[threadIdx.x];
    __syncthreads();

    const int oc = (threadIdx.x % TPR) * CPT;
    const int rt = threadIdx.x / TPR;
    const int rbase = blockIdx.x * RPB + rt;

    int rows[RPT];
#pragma unroll
    for (int i = 0; i < RPT; ++i) {
        int r = rbase + i * TROWS;
        rows[i] = (r < n) ? r : (n - 1);
    }

    float acc[RPT][3][CPT];
#pragma unroll
    for (int i = 0; i < RPT; ++i)
#pragma unroll
        for (int tt = 0; tt < 3; ++tt)
#pragma unroll
            for (int j = 0; j < CPT; ++j) acc[i][tt][j] = 0.0f;

    for (int d4 = 0; d4 < DIN; d4 += 4) {
        float4 av[RPT];
#pragma unroll
        for (int i = 0; i < RPT; ++i)
            av[i] = *reinterpret_cast<const float4*>(h + (long)rows[i] * DIN + d4);
#pragma unroll
        for (int dd = 0; dd < 4; ++dd) {
            int d = d4 + dd;
            float4 w[3][2];
#pragma unroll
            for (int tt = 0; tt < 3; ++tt) {
                const float4* wp = reinterpret_cast<const float4*>(sW + (tt * DIN + d) * DOUT + oc);
                w[tt][0] = wp[0];
                w[tt][1] = wp[1];
            }
#pragma unroll
            for (int i = 0; i < RPT; ++i) {
                float a = reinterpret_cast<const float*>(&av[i])[dd];
#pragma unroll
                for (int tt = 0; tt < 3; ++tt) {
                    const float* wf = reinterpret_cast<const float*>(&w[tt][0]);
#pragma unroll
                    for (int j = 0; j < CPT; ++j)
                        acc[i][tt][j] = fmaf(a, wf[j], acc[i][tt][j]);
                }
            }
        }
    }

#pragma unroll
    for (int i = 0; i < RPT; ++i) {
        int r = rbase + i * TROWS;
        if (r >= n) continue;
        long o = (long)r * DOUT + oc;
        float4* pp1 = reinterpret_cast<float4*>(P1 + o);
        float4* pp2 = reinterpret_cast<float4*>(P2 + o);
        float4* ps  = reinterpret_cast<float4*>(S + o);
        float sv[CPT];
#pragma unroll
        for (int j = 0; j < CPT; ++j) sv[j] = acc[i][0][j] - acc[i][2][j] + sb[oc + j];
        pp1[0] = make_float4(acc[i][1][0], acc[i][1][1], acc[i][1][2], acc[i][1][3]);
        pp1[1] = make_float4(acc[i][1][4], acc[i][1][5], acc[i][1][6], acc[i][1][7]);
        pp2[0] = make_float4(acc[i][2][0], acc[i][2][1], acc[i][2][2], acc[i][2][3]);
        pp2[1] = make_float4(acc[i][2][4], acc[i][2][5], acc[i][2][6], acc[i][2][7]);
        ps[0]  = make_float4(sv[0], sv[1], sv[2], sv[3]);
        ps[1]  = make_float4(sv[4], sv[5], sv[6], sv[7]);
    }
}

// out = sigmoid(S + Q1 + 2*Q3), elementwise float4
__global__ __launch_bounds__(256) void ewcomb_kernel(
        const float4* __restrict__ S, const float4* __restrict__ Q1,
        const float4* __restrict__ Q3, float4* __restrict__ out, long n4) {
    long i = (long)blockIdx.x * 256 + threadIdx.x;
    if (i >= n4) return;
    float4 s = S[i], q1 = Q1[i], q3 = Q3[i];
    float4 r;
    r.x = 1.0f / (1.0f + expf(-(s.x + q1.x + 2.f * q3.x)));
    r.y = 1.0f / (1.0f + expf(-(s.y + q1.y + 2.f * q3.y)));
    r.z = 1.0f / (1.0f + expf(-(s.z + q1.z + 2.f * q3.z)));
    r.w = 1.0f / (1.0f + expf(-(s.w + q1.w + 2.f * q3.w)));
    out[i] = r;
}

// ---------------- host side ----------------

static inline int ceil_div_l(long a, long b) { return (int)((a + b - 1) / b); }

template <int DIN, int DOUT>
static void run_layer(const float* h, const float* W, const float* b,
                      float* t1, float* t2, float* out,
                      const int* ofs, const int2* epk, int n, hipStream_t stream) {
    constexpr int LPN = DIN / 8;
    int ab = ceil_div_l((long)n * LPN, 256);
    agg_kernel<DIN, 0><<<ab, 256, 0, stream>>>(ofs, epk, h, nullptr, t1, n);
    agg_kernel<DIN, 1><<<ab, 256, 0, stream>>>(ofs, epk, t1, h, t2, n);
    constexpr int RPB = (256 / (DOUT / 8)) * 4;
    gemm3_kernel<DIN, DOUT><<<ceil_div_l(n, RPB), 256, 0, stream>>>(h, t1, t2, W, b, out, n);
}

extern "C" void kernel_launch(void* const* d_in, const int* in_sizes, int n_in,
                              void* d_out, int out_size, void* d_ws, size_t ws_size,
                              hipStream_t stream) {
    const float* x  = (const float*)d_in[0];
    const int*   ei = (const int*)d_in[1];
    const float* ew = (const float*)d_in[2];
    const float* W1 = (const float*)d_in[3];  const float* b1 = (const float*)d_in[4];
    const float* W2 = (const float*)d_in[5];  const float* b2 = (const float*)d_in[6];
    const float* W3 = (const float*)d_in[7];  const float* b3 = (const float*)d_in[8];
    const float* W4 = (const float*)d_in[9];  const float* b4 = (const float*)d_in[10];

    const int E = in_sizes[2];          // 1,600,000
    const int n = in_sizes[0] / 64;     // 100,000
    const int* row = ei;
    const int* col = ei + E;

    // workspace carve-up (256B aligned)
    char* ws = (char*)d_ws;
    size_t off = 0;
    auto alloc = [&](size_t bytes) -> void* {
        void* p = ws + off;
        off += (bytes + 255) & ~(size_t)255;
        return p;
    };
    float* deg    = (float*)alloc((size_t)n * sizeof(float));
    int*   cnt    = (int*)alloc((size_t)n * sizeof(int));
    int*   ofs    = (int*)alloc((size_t)(n + 1) * sizeof(int));
    int*   cursor = (int*)alloc((size_t)n * sizeof(int));
    int*   bsum   = (int*)alloc(512 * sizeof(int));
    int2*  epk    = (int2*)alloc((size_t)E * sizeof(int2));
    float* bufA   = (float*)alloc((size_t)n * 64 * sizeof(float));
    float* bufB   = (float*)alloc((size_t)n * 64 * sizeof(float));
    float* bufC   = (float*)alloc((size_t)n * 64 * sizeof(float));
    float* bufD   = (float*)alloc((size_t)n * 64 * sizeof(float));
    if (off > ws_size) return;  // fail loudly (validation) rather than corrupt

    int eb = ceil_div_l(E, 256);
    int nb = ceil_div_l(n, 256);  // 391 <= 512

    // fused degree + dest histogram
    hipMemsetAsync(deg, 0, (size_t)n * sizeof(float), stream);
    hipMemsetAsync(cnt, 0, (size_t)n * sizeof(int), stream);
    deg_hist_kernel<<<eb, 256, 0, stream>>>(row, col, ew, deg, cnt, E);

    // CSR offsets (+ cursor init fused into scan3)
    scan1_kernel<<<nb, 256, 0, stream>>>(cnt, ofs, bsum, n);
    scan2_kernel<<<1, 512, 0, stream>>>(bsum, nb);
    scan3_kernel<<<nb, 256, 0, stream>>>(ofs, cursor, bsum, n, E);
    scatter_kernel<<<eb, 256, 0, stream>>>(row, col, ew, deg, cursor, epk, E);

    // Layers 1-2: original form (Din == Dout == 64)
    run_layer<64, 64>(x,    W1, b1, bufB, bufC, bufA, ofs, epk, n, stream);
    run_layer<64, 64>(bufA, W2, b2, bufB, bufC, bufD, ofs, epk, n, stream);

    // Layer 3 (64 -> 32), commute form: props in the 32-wide output dim.
    // P1 = h@W1, P2 = h@W2, S = h@W0 - P2 + b; out = sigma(S + L@P1 + 2*L@(L@P2))
    {
        const float* h = bufD;
        float* P1 = bufA;                 // n x 32
        float* P2 = bufA + (long)n * 32;  // n x 32
        float* S  = bufB;                 // n x 32
        float* Q1 = bufB + (long)n * 32;  // n x 32
        float* Q2 = bufC;                 // n x 32
        float* Q3 = bufC + (long)n * 32;  // n x 32
        gemm_multi_kernel<64, 32><<<ceil_div_l(n, 128), 256, 0, stream>>>(h, W3, b3, P1, P2, S, n);
        int ab32 = ceil_div_l((long)n * 4, 256);
        agg_kernel<32, 0><<<ab32, 256, 0, stream>>>(ofs, epk, P1, nullptr, Q1, n);
        agg_kernel<32, 0><<<ab32, 256, 0, stream>>>(ofs, epk, P2, nullptr, Q2, n);
        agg_kernel<32, 0><<<ab32, 256, 0, stream>>>(ofs, epk, Q2, nullptr, Q3, n);
        long n4 = (long)n * 32 / 4;
        ewcomb_kernel<<<ceil_div_l(n4, 256), 256, 0, stream>>>(
            (const float4*)S, (const float4*)Q1, (const float4*)Q3, (float4*)bufD, n4);
    }

    // Layer 4 (32 -> 16): original form, h = bufD (n x 32)
    run_layer<32, 16>(bufD, W4, b4, bufA, bufB, (float*)d_out, ofs, epk, n, stream);
}

// Round 5
// 660.178 us; speedup vs baseline: 15.2372x; 1.2466x over previous
//
#include <hip/hip_runtime.h>
#include <math.h>

// ChebNet: 4 layers of ChebConv(K=3) + sigmoid.
// norm = -D^{-1/2} A D^{-1/2} (self loops removed)
// per layer: t1 = L@h ; U = L@t1 ; out = sigmoid(h@(W0-W2) + t1@W1 + U@(2*W2) + b)
//   (t2 = 2U - h algebraically folded into the weights)
//
// R1: atomic scatter -> CSR gather; 10.06ms -> 1.28ms
// R2: register-tiled gemm3, fused CSR build; -> 0.949ms
// R3: packed edges, 4-edge unroll, layer-3 commute form; -> 0.823ms
// R4: 4x-replicated histograms (line-contention fix) + rank trick (atomic-free
//     scatter), bf16 gathers (half gather bytes), t2 folded into gemm weights.

typedef __attribute__((ext_vector_type(8))) short short8_t;
typedef __attribute__((ext_vector_type(4))) short short4_t;

__device__ __forceinline__ float bf2f(short s) {
    return __int_as_float(((int)(unsigned short)s) << 16);
}
__device__ __forceinline__ short f2bf(float f) {  // round-to-nearest-even
    unsigned u = __float_as_uint(f);
    return (short)((u + 0x7FFFu + ((u >> 16) & 1u)) >> 16);
}

// ---------------- fp32 -> bf16 convert ----------------

__global__ __launch_bounds__(256) void f2b_kernel(
        const float* __restrict__ in, short* __restrict__ out, long m) {
    long i = ((long)blockIdx.x * 256 + threadIdx.x) * 4;
    if (i >= m) return;
    float4 v = *reinterpret_cast<const float4*>(in + i);
    short4_t s;
    s[0] = f2bf(v.x); s[1] = f2bf(v.y); s[2] = f2bf(v.z); s[3] = f2bf(v.w);
    *reinterpret_cast<short4_t*>(out + i) = s;
}

// ---------------- degree + replicated histogram + rank ----------------

__global__ __launch_bounds__(256) void deg_hist_kernel(
        const int* __restrict__ row, const int* __restrict__ col,
        const float* __restrict__ ew, float* __restrict__ deg_r,
        int* __restrict__ cnt_r, int* __restrict__ rank, int n, int E) {
    int e = blockIdx.x * 256 + threadIdx.x;
    if (e >= E) return;
    int cp = blockIdx.x & 3;
    int r = row[e], c = col[e];
    float w = (r == c) ? 0.0f : ew[e];
    if (w != 0.0f) atomicAdd(&deg_r[cp * n + r], w);
    rank[e] = atomicAdd(&cnt_r[cp * n + c], 1);
}

__global__ __launch_bounds__(256) void deg_reduce_kernel(
        const float* __restrict__ deg_r, float* __restrict__ deg, int n) {
    int i = blockIdx.x * 256 + threadIdx.x;
    if (i >= n) return;
    deg[i] = deg_r[i] + deg_r[n + i] + deg_r[2 * n + i] + deg_r[3 * n + i];
}

// ---------------- scan over M=4n buckets, order (c, cp) c-major ----------------

__global__ __launch_bounds__(512) void scan1_kernel(
        const int* __restrict__ cnt_r, int* __restrict__ ofs2,
        int* __restrict__ bsum, int n) {
    __shared__ int sh[512];
    int M = 4 * n;
    int j = blockIdx.x * 512 + threadIdx.x;
    int v = (j < M) ? cnt_r[(j & 3) * n + (j >> 2)] : 0;
    sh[threadIdx.x] = v;
    __syncthreads();
    for (int o = 1; o < 512; o <<= 1) {
        int t = (threadIdx.x >= o) ? sh[threadIdx.x - o] : 0;
        __syncthreads();
        sh[threadIdx.x] += t;
        __syncthreads();
    }
    if (j < M) ofs2[j] = sh[threadIdx.x] - v;  // exclusive
    if (threadIdx.x == 511) bsum[blockIdx.x] = sh[511];
}

__global__ __launch_bounds__(1024) void scan2_kernel(int* __restrict__ bsum, int nb) {
    __shared__ int sh[1024];
    int v = (threadIdx.x < nb) ? bsum[threadIdx.x] : 0;
    sh[threadIdx.x] = v;
    __syncthreads();
    for (int o = 1; o < 1024; o <<= 1) {
        int t = (threadIdx.x >= o) ? sh[threadIdx.x - o] : 0;
        __syncthreads();
        sh[threadIdx.x] += t;
        __syncthreads();
    }
    if (threadIdx.x < nb) bsum[threadIdx.x] = sh[threadIdx.x] - v;
}

__global__ __launch_bounds__(512) void scan3_kernel(
        int* __restrict__ ofs2, const int* __restrict__ bsum, int M, int E) {
    int j = blockIdx.x * 512 + threadIdx.x;
    if (j < M) ofs2[j] += bsum[blockIdx.x];
    if (j == 0) ofs2[M] = E;  // sentinel
}

// ---------------- atomic-free scatter (position from ofs2 + rank) ----------------

__global__ __launch_bounds__(256) void scatter_kernel(
        const int* __restrict__ row, const int* __restrict__ col,
        const float* __restrict__ ew, const float* __restrict__ deg,
        const int* __restrict__ rank, const int* __restrict__ ofs2,
        int2* __restrict__ epk, int E) {
    int e = blockIdx.x * 256 + threadIdx.x;
    if (e >= E) return;
    int cp = blockIdx.x & 3;
    int r = row[e], c = col[e];
    float w = (r == c) ? 0.0f : ew[e];
    float dr = deg[r], dc = deg[c];
    float ir = dr > 0.0f ? rsqrtf(dr) : 0.0f;
    float ic = dc > 0.0f ? rsqrtf(dc) : 0.0f;
    int p = ofs2[(c << 2) | cp] + rank[e];
    epk[p] = make_int2(r, __float_as_int(-ir * w * ic));
}

// ---------------- aggregation (bf16 gather, fp32 accumulate) ----------------
// out[node] = sum_k val[k] * tb[src[k]]; OUTB selects bf16 vs fp32 output.

template <int D, bool OUTB>
__global__ __launch_bounds__(256) void agg_kernel(
        const int* __restrict__ ofs2, const int2* __restrict__ epk,
        const short* __restrict__ tb, float* __restrict__ outf,
        short* __restrict__ outb, int n) {
    constexpr int LPN = D / 8;  // 8 bf16 (16B) per lane
    int idx = blockIdx.x * 256 + threadIdx.x;
    int node = idx / LPN;
    int l = idx % LPN;
    if (node >= n) return;
    int beg = ofs2[node << 2], end = ofs2[(node << 2) + 4];
    float a[8] = {0.f, 0.f, 0.f, 0.f, 0.f, 0.f, 0.f, 0.f};
    const short* tc = tb + l * 8;
    int k = beg;
    for (; k + 4 <= end; k += 4) {
        int2 ev[4];
        short8_t xv[4];
#pragma unroll
        for (int u = 0; u < 4; ++u) ev[u] = epk[k + u];
#pragma unroll
        for (int u = 0; u < 4; ++u)
            xv[u] = *reinterpret_cast<const short8_t*>(tc + (long)ev[u].x * D);
#pragma unroll
        for (int u = 0; u < 4; ++u) {
            float v = __int_as_float(ev[u].y);
#pragma unroll
            for (int j = 0; j < 8; ++j) a[j] = fmaf(v, bf2f(xv[u][j]), a[j]);
        }
    }
    for (; k < end; ++k) {
        int2 e0 = epk[k];
        short8_t x0 = *reinterpret_cast<const short8_t*>(tc + (long)e0.x * D);
        float v = __int_as_float(e0.y);
#pragma unroll
        for (int j = 0; j < 8; ++j) a[j] = fmaf(v, bf2f(x0[j]), a[j]);
    }
    long o = (long)node * D + l * 8;
    if (OUTB) {
        short8_t s;
#pragma unroll
        for (int j = 0; j < 8; ++j) s[j] = f2bf(a[j]);
        *reinterpret_cast<short8_t*>(outb + o) = s;
    } else {
        *reinterpret_cast<float4*>(outf + o) = make_float4(a[0], a[1], a[2], a[3]);
        *reinterpret_cast<float4*>(outf + o + 4) = make_float4(a[4], a[5], a[6], a[7]);
    }
}

// ---------------- fused GEMM + bias + sigmoid (t2 folded) ----------------
// out = sigmoid(t0@(W0-W2) + t1@W1 + U@(2*W2) + b); t0,U fp32; t1 bf16.

template <int DIN, int DOUT, bool MIRROR>
__global__ __launch_bounds__(256) void gemm3_kernel(
        const float* __restrict__ t0, const short* __restrict__ t1b,
        const float* __restrict__ t2, const float* __restrict__ W,
        const float* __restrict__ b, float* __restrict__ out,
        short* __restrict__ outb, int n) {
    constexpr int CPT = 8;
    constexpr int RPT = 4;
    constexpr int TPR = DOUT / CPT;
    constexpr int TROWS = 256 / TPR;
    constexpr int RPB = TROWS * RPT;
    constexpr int P = DIN * DOUT;

    __shared__ float sW[3 * P];
    __shared__ float sb[DOUT];
    for (int i = threadIdx.x; i < P; i += 256) {
        float w0 = W[i], w1 = W[P + i], w2 = W[2 * P + i];
        sW[i] = w0 - w2;
        sW[P + i] = w1;
        sW[2 * P + i] = 2.0f * w2;
    }
    if (threadIdx.x < DOUT) sb[threadIdx.x] = b[threadIdx.x];
    __syncthreads();

    const int oc = (threadIdx.x % TPR) * CPT;
    const int rt = threadIdx.x / TPR;
    const int rbase = blockIdx.x * RPB + rt;

    int rows[RPT];
#pragma unroll
    for (int i = 0; i < RPT; ++i) {
        int r = rbase + i * TROWS;
        rows[i] = (r < n) ? r : (n - 1);
    }

    float acc[RPT][CPT];
#pragma unroll
    for (int i = 0; i < RPT; ++i)
#pragma unroll
        for (int j = 0; j < CPT; ++j) acc[i][j] = 0.0f;

    for (int d4 = 0; d4 < DIN; d4 += 4) {
        float4 av0[RPT], av2[RPT];
        short4_t av1[RPT];
#pragma unroll
        for (int i = 0; i < RPT; ++i) {
            av0[i] = *reinterpret_cast<const float4*>(t0 + (long)rows[i] * DIN + d4);
            av1[i] = *reinterpret_cast<const short4_t*>(t1b + (long)rows[i] * DIN + d4);
            av2[i] = *reinterpret_cast<const float4*>(t2 + (long)rows[i] * DIN + d4);
        }
#pragma unroll
        for (int dd = 0; dd < 4; ++dd) {
            int d = d4 + dd;
            float4 w0[2], w1[2], w2[2];
            {
                const float4* wp0 = reinterpret_cast<const float4*>(sW + d * DOUT + oc);
                const float4* wp1 = reinterpret_cast<const float4*>(sW + P + d * DOUT + oc);
                const float4* wp2 = reinterpret_cast<const float4*>(sW + 2 * P + d * DOUT + oc);
                w0[0] = wp0[0]; w0[1] = wp0[1];
                w1[0] = wp1[0]; w1[1] = wp1[1];
                w2[0] = wp2[0]; w2[1] = wp2[1];
            }
            const float* wf0 = reinterpret_cast<const float*>(&w0[0]);
            const float* wf1 = reinterpret_cast<const float*>(&w1[0]);
            const float* wf2 = reinterpret_cast<const float*>(&w2[0]);
#pragma unroll
            for (int i = 0; i < RPT; ++i) {
                float a0 = reinterpret_cast<const float*>(&av0[i])[dd];
                float a1 = bf2f(av1[i][dd]);
                float a2 = reinterpret_cast<const float*>(&av2[i])[dd];
#pragma unroll
                for (int j = 0; j < CPT; ++j) {
                    acc[i][j] = fmaf(a0, wf0[j], acc[i][j]);
                    acc[i][j] = fmaf(a1, wf1[j], acc[i][j]);
                    acc[i][j] = fmaf(a2, wf2[j], acc[i][j]);
                }
            }
        }
    }

#pragma unroll
    for (int i = 0; i < RPT; ++i) {
        int r = rbase + i * TROWS;
        if (r >= n) continue;
        float res[CPT];
#pragma unroll
        for (int j = 0; j < CPT; ++j) {
            float z = acc[i][j] + sb[oc + j];
            res[j] = 1.0f / (1.0f + expf(-z));
        }
        long o = (long)r * DOUT + oc;
        float4* po = reinterpret_cast<float4*>(out + o);
        po[0] = make_float4(res[0], res[1], res[2], res[3]);
        po[1] = make_float4(res[4], res[5], res[6], res[7]);
        if (MIRROR) {
            short8_t s;
#pragma unroll
            for (int j = 0; j < CPT; ++j) s[j] = f2bf(res[j]);
            *reinterpret_cast<short8_t*>(outb + o) = s;
        }
    }
}

// ---------------- multi-output GEMM for commute-form layer 3 ----------------
// P1 = h@W1 (bf16), P2 = h@W2 (bf16), S = h@(W0-W2) + b (fp32)

template <int DIN, int DOUT>
__global__ __launch_bounds__(256) void gemm_multi_kernel(
        const float* __restrict__ h, const float* __restrict__ W,
        const float* __restrict__ b, short* __restrict__ P1b,
        short* __restrict__ P2b, float* __restrict__ S, int n) {
    constexpr int CPT = 8;
    constexpr int RPT = 2;
    constexpr int TPR = DOUT / CPT;   // 4
    constexpr int TROWS = 256 / TPR;  // 64
    constexpr int RPB = TROWS * RPT;  // 128
    constexpr int P = DIN * DOUT;

    __shared__ float sW[3 * P];
    __shared__ float sb[DOUT];
    for (int i = threadIdx.x; i < P; i += 256) {
        float w0 = W[i], w1 = W[P + i], w2 = W[2 * P + i];
        sW[i] = w0 - w2;   // S plane
        sW[P + i] = w1;    // P1 plane
        sW[2 * P + i] = w2;  // P2 plane
    }
    if (threadIdx.x < DOUT) sb[threadIdx.x] = b[threadIdx.x];
    __syncthreads();

    const int oc = (threadIdx.x % TPR) * CPT;
    const int rt = threadIdx.x / TPR;
    const int rbase = blockIdx.x * RPB + rt;

    int rows[RPT];
#pragma unroll
    for (int i = 0; i < RPT; ++i) {
        int r = rbase + i * TROWS;
        rows[i] = (r < n) ? r : (n - 1);
    }

    float acc[RPT][3][CPT];
#pragma unroll
    for (int i = 0; i < RPT; ++i)
#pragma unroll
        for (int tt = 0; tt < 3; ++tt)
#pragma unroll
            for (int j = 0; j < CPT; ++j) acc[i][tt][j] = 0.0f;

    for (int d4 = 0; d4 < DIN; d4 += 4) {
        float4 av[RPT];
#pragma unroll
        for (int i = 0; i < RPT; ++i)
            av[i] = *reinterpret_cast<const float4*>(h + (long)rows[i] * DIN + d4);
#pragma unroll
        for (int dd = 0; dd < 4; ++dd) {
            int d = d4 + dd;
            float4 w[3][2];
#pragma unroll
            for (int tt = 0; tt < 3; ++tt) {
                const float4* wp = reinterpret_cast<const float4*>(sW + tt * P + d * DOUT + oc);
                w[tt][0] = wp[0];
                w[tt][1] = wp[1];
            }
#pragma unroll
            for (int i = 0; i < RPT; ++i) {
                float a = reinterpret_cast<const float*>(&av[i])[dd];
#pragma unroll
                for (int tt = 0; tt < 3; ++tt) {
                    const float* wf = reinterpret_cast<const float*>(&w[tt][0]);
#pragma unroll
                    for (int j = 0; j < CPT; ++j)
                        acc[i][tt][j] = fmaf(a, wf[j], acc[i][tt][j]);
                }
            }
        }
    }

#pragma unroll
    for (int i = 0; i < RPT; ++i) {
        int r = rbase + i * TROWS;
        if (r >= n) continue;
        long o = (long)r * DOUT + oc;
        short8_t s1, s2;
#pragma unroll
        for (int j = 0; j < CPT; ++j) {
            s1[j] = f2bf(acc[i][1][j]);
            s2[j] = f2bf(acc[i][2][j]);
        }
        *reinterpret_cast<short8_t*>(P1b + o) = s1;
        *reinterpret_cast<short8_t*>(P2b + o) = s2;
        float4* ps = reinterpret_cast<float4*>(S + o);
        ps[0] = make_float4(acc[i][0][0] + sb[oc], acc[i][0][1] + sb[oc + 1],
                            acc[i][0][2] + sb[oc + 2], acc[i][0][3] + sb[oc + 3]);
        ps[1] = make_float4(acc[i][0][4] + sb[oc + 4], acc[i][0][5] + sb[oc + 5],
                            acc[i][0][6] + sb[oc + 6], acc[i][0][7] + sb[oc + 7]);
    }
}

// out = sigmoid(S + Q1 + 2*Q3), fp32 + bf16 mirror
__global__ __launch_bounds__(256) void ewcomb_kernel(
        const float4* __restrict__ S, const float4* __restrict__ Q1,
        const float4* __restrict__ Q3, float4* __restrict__ out,
        short* __restrict__ outb, long n4) {
    long i = (long)blockIdx.x * 256 + threadIdx.x;
    if (i >= n4) return;
    float4 s = S[i], q1 = Q1[i], q3 = Q3[i];
    float4 r;
    r.x = 1.0f / (1.0f + expf(-(s.x + q1.x + 2.f * q3.x)));
    r.y = 1.0f / (1.0f + expf(-(s.y + q1.y + 2.f * q3.y)));
    r.z = 1.0f / (1.0f + expf(-(s.z + q1.z + 2.f * q3.z)));
    r.w = 1.0f / (1.0f + expf(-(s.w + q1.w + 2.f * q3.w)));
    out[i] = r;
    short4_t sb4;
    sb4[0] = f2bf(r.x); sb4[1] = f2bf(r.y); sb4[2] = f2bf(r.z); sb4[3] = f2bf(r.w);
    *reinterpret_cast<short4_t*>(outb + i * 4) = sb4;
}

// ---------------- host side ----------------

static inline int ceil_div_l(long a, long b) { return (int)((a + b - 1) / b); }

extern "C" void kernel_launch(void* const* d_in, const int* in_sizes, int n_in,
                              void* d_out, int out_size, void* d_ws, size_t ws_size,
                              hipStream_t stream) {
    const float* x  = (const float*)d_in[0];
    const int*   ei = (const int*)d_in[1];
    const float* ew = (const float*)d_in[2];
    const float* W1 = (const float*)d_in[3];  const float* b1 = (const float*)d_in[4];
    const float* W2 = (const float*)d_in[5];  const float* b2 = (const float*)d_in[6];
    const float* W3 = (const float*)d_in[7];  const float* b3 = (const float*)d_in[8];
    const float* W4 = (const float*)d_in[9];  const float* b4 = (const float*)d_in[10];

    const int E = in_sizes[2];          // 1,600,000
    const int n = in_sizes[0] / 64;     // 100,000
    const int* row = ei;
    const int* col = ei + E;

    // workspace carve-up (256B aligned)
    char* ws = (char*)d_ws;
    size_t off = 0;
    auto alloc = [&](size_t bytes) -> void* {
        void* p = ws + off;
        off += (bytes + 255) & ~(size_t)255;
        return p;
    };
    float* deg_r = (float*)alloc((size_t)4 * n * sizeof(float));
    int*   cnt_r = (int*)alloc((size_t)4 * n * sizeof(int));
    float* deg   = (float*)alloc((size_t)n * sizeof(float));
    int*   ofs2  = (int*)alloc(((size_t)4 * n + 1) * sizeof(int));
    int*   bsum  = (int*)alloc(1024 * sizeof(int));
    int*   rank  = (int*)alloc((size_t)E * sizeof(int));
    int2*  epk   = (int2*)alloc((size_t)E * sizeof(int2));
    float* X     = (float*)alloc((size_t)n * 64 * sizeof(float));
    float* Z     = (float*)alloc((size_t)n * 64 * sizeof(float));
    short* T1b   = (short*)alloc((size_t)n * 64 * sizeof(short));
    short* mX    = (short*)alloc((size_t)n * 64 * sizeof(short));
    if (off > ws_size) return;  // fail loudly (validation) rather than corrupt

    const int eb = ceil_div_l(E, 256);
    const int M = 4 * n;
    const int nb1 = ceil_div_l(M, 512);  // 782 <= 1024

    // bf16 copy of x for layer-1 gathers
    f2b_kernel<<<ceil_div_l((long)n * 16, 256), 256, 0, stream>>>(x, mX, (long)n * 64);

    // degree + replicated histogram + per-edge rank
    hipMemsetAsync(deg_r, 0, (size_t)4 * n * sizeof(float), stream);
    hipMemsetAsync(cnt_r, 0, (size_t)4 * n * sizeof(int), stream);
    deg_hist_kernel<<<eb, 256, 0, stream>>>(row, col, ew, deg_r, cnt_r, rank, n, E);
    deg_reduce_kernel<<<ceil_div_l(n, 256), 256, 0, stream>>>(deg_r, deg, n);

    // CSR offsets over (col, copy) buckets
    scan1_kernel<<<nb1, 512, 0, stream>>>(cnt_r, ofs2, bsum, n);
    scan2_kernel<<<1, 1024, 0, stream>>>(bsum, nb1);
    scan3_kernel<<<nb1, 512, 0, stream>>>(ofs2, bsum, M, E);

    // atomic-free scatter
    scatter_kernel<<<eb, 256, 0, stream>>>(row, col, ew, deg, rank, ofs2, epk, E);

    const int ab64 = ceil_div_l((long)n * 8, 256);
    const int ab32 = ceil_div_l((long)n * 4, 256);

    // Layer 1 (h = x): t1 -> T1b(bf16), U -> Z, out -> X + mirror mX
    agg_kernel<64, true><<<ab64, 256, 0, stream>>>(ofs2, epk, mX, nullptr, T1b, n);
    agg_kernel<64, false><<<ab64, 256, 0, stream>>>(ofs2, epk, T1b, Z, nullptr, n);
    gemm3_kernel<64, 64, true><<<ceil_div_l(n, 128), 256, 0, stream>>>(
        x, T1b, Z, W1, b1, X, mX, n);

    // Layer 2
    agg_kernel<64, true><<<ab64, 256, 0, stream>>>(ofs2, epk, mX, nullptr, T1b, n);
    agg_kernel<64, false><<<ab64, 256, 0, stream>>>(ofs2, epk, T1b, Z, nullptr, n);
    gemm3_kernel<64, 64, true><<<ceil_div_l(n, 128), 256, 0, stream>>>(
        X, T1b, Z, W2, b2, X, mX, n);

    // Layer 3 (64 -> 32), commute form: props in 32-dim.
    // P1=h@W1, P2=h@W2 (bf16), S=h@(W0-W2)+b; out = sigma(S + L@P1 + 2*L@(L@P2))
    {
        short* P1b = T1b;                  // n x 32 bf16
        short* P2b = T1b + (size_t)n * 32; // n x 32 bf16
        float* S   = Z;                    // n x 32 f32
        float* Q1  = Z + (size_t)n * 32;   // n x 32 f32
        short* Q2b = mX;                   // n x 32 bf16 (h2 mirror dead)
        float* Q3  = X;                    // n x 32 f32 (h3 dead after gemm_multi)
        float* h4  = X + (size_t)n * 32;   // n x 32 f32
        gemm_multi_kernel<64, 32><<<ceil_div_l(n, 128), 256, 0, stream>>>(
            X, W3, b3, P1b, P2b, S, n);
        agg_kernel<32, false><<<ab32, 256, 0, stream>>>(ofs2, epk, P1b, Q1, nullptr, n);
        agg_kernel<32, true><<<ab32, 256, 0, stream>>>(ofs2, epk, P2b, nullptr, Q2b, n);
        agg_kernel<32, false><<<ab32, 256, 0, stream>>>(ofs2, epk, Q2b, Q3, nullptr, n);
        long n4 = (long)n * 8;  // n*32/4
        ewcomb_kernel<<<ceil_div_l(n4, 256), 256, 0, stream>>>(
            (const float4*)S, (const float4*)Q1, (const float4*)Q3,
            (float4*)h4, mX /* h4 bf16 mirror */, n4);
    }

    // Layer 4 (32 -> 16): h4 = X + n*32 (fp32), mirror mX[0:n*32]
    agg_kernel<32, true><<<ab32, 256, 0, stream>>>(ofs2, epk, mX, nullptr, T1b, n);
    agg_kernel<32, false><<<ab32, 256, 0, stream>>>(ofs2, epk, T1b, Z, nullptr, n);
    gemm3_kernel<32, 16, false><<<ceil_div_l(n, 512), 256, 0, stream>>>(
        X + (size_t)n * 32, T1b, Z, W4, b4, (float*)d_out, nullptr, n);
}

// Round 6
// 518.832 us; speedup vs baseline: 19.3882x; 1.2724x over previous
//
#include <hip/hip_runtime.h>
#include <math.h>

// ChebNet: 4 layers of ChebConv(K=3) + sigmoid.
// norm = -D^{-1/2} A D^{-1/2} (self loops removed)
// per layer: t1 = L@h ; U = L@t1 ; out = sigmoid(h@(W0-W2) + t1@W1 + U@(2*W2) + b)
//
// R1: atomic scatter -> CSR gather; 10.06ms -> 1.28ms
// R2: register-tiled gemm3, fused CSR build; -> 0.949ms
// R3: packed edges, 4-edge unroll, layer-3 commute form; -> 0.823ms
// R4: bf16 gathers, t2 folded into weights, rank trick; -> 0.660ms
// R5: two-level partition CSR build (global atomics 3.2M -> ~0.3M; LDS
//     histograms/accumulate), ofs written per-partition (drops 4n scan),
//     fused dual agg for layer-3's independent props.

typedef __attribute__((ext_vector_type(8))) short short8_t;
typedef __attribute__((ext_vector_type(4))) short short4_t;

#define NPP 256          // nodes per partition
#define CHUNK 8192       // edges per block in count/scatter passes

__device__ __forceinline__ float bf2f(short s) {
    return __int_as_float(((int)(unsigned short)s) << 16);
}
__device__ __forceinline__ short f2bf(float f) {  // round-to-nearest-even
    unsigned u = __float_as_uint(f);
    return (short)((u + 0x7FFFu + ((u >> 16) & 1u)) >> 16);
}

// ---------------- fp32 -> bf16 convert ----------------

__global__ __launch_bounds__(256) void f2b_kernel(
        const float* __restrict__ in, short* __restrict__ out, long m) {
    long i = ((long)blockIdx.x * 256 + threadIdx.x) * 4;
    if (i >= m) return;
    float4 v = *reinterpret_cast<const float4*>(in + i);
    short4_t s;
    s[0] = f2bf(v.x); s[1] = f2bf(v.y); s[2] = f2bf(v.z); s[3] = f2bf(v.w);
    *reinterpret_cast<short4_t*>(out + i) = s;
}

// ---------------- A: coarse partition counts (col and row) ----------------

__global__ __launch_bounds__(256) void part_count_kernel(
        const int* __restrict__ row, const int* __restrict__ col,
        int* __restrict__ pcnt, int* __restrict__ rcnt, int P, int E) {
    __shared__ int hc[512], hr[512];
    for (int i = threadIdx.x; i < P; i += 256) { hc[i] = 0; hr[i] = 0; }
    __syncthreads();
    int base = blockIdx.x * CHUNK;
    int lim = min(E, base + CHUNK);
    for (int e = base + threadIdx.x; e < lim; e += 256) {
        atomicAdd(&hc[col[e] >> 8], 1);
        atomicAdd(&hr[row[e] >> 8], 1);
    }
    __syncthreads();
    for (int i = threadIdx.x; i < P; i += 256) {
        if (hc[i]) atomicAdd(&pcnt[i], hc[i]);
        if (hr[i]) atomicAdd(&rcnt[i], hr[i]);
    }
}

// ---------------- scan of partition counts (P <= 512) ----------------

__global__ __launch_bounds__(512) void part_scan_kernel(
        const int* __restrict__ pcnt, const int* __restrict__ rcnt,
        int* __restrict__ pofs, int* __restrict__ pcur,
        int* __restrict__ rofs, int* __restrict__ rcur,
        int* __restrict__ ofs, int P, int n, int E) {
    __shared__ int sh[512];
    int tid = threadIdx.x;
    int v = (tid < P) ? pcnt[tid] : 0;
    sh[tid] = v;
    __syncthreads();
    for (int o = 1; o < 512; o <<= 1) {
        int t = (tid >= o) ? sh[tid - o] : 0;
        __syncthreads();
        sh[tid] += t;
        __syncthreads();
    }
    if (tid < P) { int ex = sh[tid] - v; pofs[tid] = ex; pcur[tid] = ex; }
    if (tid == 0) pofs[P] = E;
    __syncthreads();
    v = (tid < P) ? rcnt[tid] : 0;
    sh[tid] = v;
    __syncthreads();
    for (int o = 1; o < 512; o <<= 1) {
        int t = (tid >= o) ? sh[tid - o] : 0;
        __syncthreads();
        sh[tid] += t;
        __syncthreads();
    }
    if (tid < P) { int ex = sh[tid] - v; rofs[tid] = ex; rcur[tid] = ex; }
    if (tid == 0) { rofs[P] = E; ofs[n] = E; }
}

// ---------------- C: scatter edges into partition buckets ----------------
// bufC[p-range]: (finec<<24 | row, w_masked)   bufR[p-range]: (finer, w_masked)

__global__ __launch_bounds__(256) void part_scatter_kernel(
        const int* __restrict__ row, const int* __restrict__ col,
        const float* __restrict__ ew, int* __restrict__ pcur,
        int* __restrict__ rcur, int2* __restrict__ bufC,
        int2* __restrict__ bufR, int P, int E) {
    __shared__ int hc[512], hr[512];
    for (int i = threadIdx.x; i < P; i += 256) { hc[i] = 0; hr[i] = 0; }
    __syncthreads();
    int base = blockIdx.x * CHUNK;
    int lim = min(E, base + CHUNK);
    for (int e = base + threadIdx.x; e < lim; e += 256) {
        atomicAdd(&hc[col[e] >> 8], 1);
        atomicAdd(&hr[row[e] >> 8], 1);
    }
    __syncthreads();
    // reserve global ranges; hc/hr become global cursors
    for (int i = threadIdx.x; i < P; i += 256) {
        int c = hc[i]; hc[i] = c ? atomicAdd(&pcur[i], c) : 0;
        int r = hr[i]; hr[i] = r ? atomicAdd(&rcur[i], r) : 0;
    }
    __syncthreads();
    for (int e = base + threadIdx.x; e < lim; e += 256) {
        int r = row[e], c = col[e];
        float w = (r == c) ? 0.0f : ew[e];
        int wb = __float_as_int(w);
        int pc = atomicAdd(&hc[c >> 8], 1);
        bufC[pc] = make_int2((int)(((unsigned)(c & 255) << 24) | (unsigned)r), wb);
        int pr = atomicAdd(&hr[r >> 8], 1);
        bufR[pr] = make_int2(r & 255, wb);
    }
}

// ---------------- F: per-row-partition degree accumulate -> dinv ----------------

__global__ __launch_bounds__(256) void dinv_kernel(
        const int2* __restrict__ bufR, const int* __restrict__ rofs,
        float* __restrict__ dinv, int n) {
    int p = blockIdx.x;
    __shared__ float s[NPP];
    s[threadIdx.x] = 0.0f;
    __syncthreads();
    int beg = rofs[p], end = rofs[p + 1];
    for (int k = beg + threadIdx.x; k < end; k += 256) {
        int2 e = bufR[k];
        atomicAdd(&s[e.x], __int_as_float(e.y));
    }
    __syncthreads();
    int node = (p << 8) + threadIdx.x;
    if (node < n) {
        float d = s[threadIdx.x];
        dinv[node] = d > 0.0f ? rsqrtf(d) : 0.0f;
    }
}

// ---------------- E: fine CSR within each col partition + norm ----------------

__global__ __launch_bounds__(256) void fine_csr_kernel(
        const int2* __restrict__ bufC, const int* __restrict__ pofs,
        const float* __restrict__ dinv, int* __restrict__ ofs,
        int2* __restrict__ epk, int n) {
    int p = blockIdx.x;
    int tid = threadIdx.x;
    __shared__ int hist[NPP];
    __shared__ int sc[NPP];
    __shared__ float dc[NPP];
    hist[tid] = 0;
    int node = (p << 8) + tid;
    dc[tid] = (node < n) ? dinv[node] : 0.0f;
    __syncthreads();
    int beg = pofs[p], end = pofs[p + 1];
    for (int k = beg + tid; k < end; k += 256)
        atomicAdd(&hist[((unsigned)bufC[k].x) >> 24], 1);
    __syncthreads();
    int v = hist[tid];
    sc[tid] = v;
    __syncthreads();
    for (int o = 1; o < 256; o <<= 1) {
        int t = (tid >= o) ? sc[tid - o] : 0;
        __syncthreads();
        sc[tid] += t;
        __syncthreads();
    }
    int mybase = beg + sc[tid] - v;  // exclusive
    if (node < n) ofs[node] = mybase;
    hist[tid] = mybase;  // becomes cursor
    __syncthreads();
    for (int k = beg + tid; k < end; k += 256) {
        int2 ed = bufC[k];
        unsigned key = (unsigned)ed.x;
        int fc = key >> 24;
        int r = (int)(key & 0xFFFFFFu);
        float w = __int_as_float(ed.y);
        float nrm = -dinv[r] * w * dc[fc];
        int pos = atomicAdd(&hist[fc], 1);
        epk[pos] = make_int2(r, __float_as_int(nrm));
    }
}

// ---------------- aggregation (bf16 gather, fp32 accumulate) ----------------

template <int D, bool OUTB>
__global__ __launch_bounds__(256) void agg_kernel(
        const int* __restrict__ ofs, const int2* __restrict__ epk,
        const short* __restrict__ tb, float* __restrict__ outf,
        short* __restrict__ outb, int n) {
    constexpr int LPN = D / 8;
    int idx = blockIdx.x * 256 + threadIdx.x;
    int node = idx / LPN;
    int l = idx % LPN;
    if (node >= n) return;
    int beg = ofs[node], end = ofs[node + 1];
    float a[8] = {0.f, 0.f, 0.f, 0.f, 0.f, 0.f, 0.f, 0.f};
    const short* tc = tb + l * 8;
    int k = beg;
    for (; k + 4 <= end; k += 4) {
        int2 ev[4];
        short8_t xv[4];
#pragma unroll
        for (int u = 0; u < 4; ++u) ev[u] = epk[k + u];
#pragma unroll
        for (int u = 0; u < 4; ++u)
            xv[u] = *reinterpret_cast<const short8_t*>(tc + (long)ev[u].x * D);
#pragma unroll
        for (int u = 0; u < 4; ++u) {
            float v = __int_as_float(ev[u].y);
#pragma unroll
            for (int j = 0; j < 8; ++j) a[j] = fmaf(v, bf2f(xv[u][j]), a[j]);
        }
    }
    for (; k < end; ++k) {
        int2 e0 = epk[k];
        short8_t x0 = *reinterpret_cast<const short8_t*>(tc + (long)e0.x * D);
        float v = __int_as_float(e0.y);
#pragma unroll
        for (int j = 0; j < 8; ++j) a[j] = fmaf(v, bf2f(x0[j]), a[j]);
    }
    long o = (long)node * D + l * 8;
    if (OUTB) {
        short8_t s;
#pragma unroll
        for (int j = 0; j < 8; ++j) s[j] = f2bf(a[j]);
        *reinterpret_cast<short8_t*>(outb + o) = s;
    } else {
        *reinterpret_cast<float4*>(outf + o) = make_float4(a[0], a[1], a[2], a[3]);
        *reinterpret_cast<float4*>(outf + o + 4) = make_float4(a[4], a[5], a[6], a[7]);
    }
}

// Dual agg for layer 3: tb is [n][64] = [P1|P2] bf16; lanes 0-3 -> Q1 (f32
// [n][32]), lanes 4-7 -> Q2 (bf16 [n][32]).

__global__ __launch_bounds__(256) void agg_dual_kernel(
        const int* __restrict__ ofs, const int2* __restrict__ epk,
        const short* __restrict__ tb, float* __restrict__ outf,
        short* __restrict__ outb, int n) {
    int idx = blockIdx.x * 256 + threadIdx.x;
    int node = idx >> 3;
    int l = idx & 7;
    if (node >= n) return;
    int beg = ofs[node], end = ofs[node + 1];
    float a[8] = {0.f, 0.f, 0.f, 0.f, 0.f, 0.f, 0.f, 0.f};
    const short* tc = tb + l * 8;
    int k = beg;
    for (; k + 4 <= end; k += 4) {
        int2 ev[4];
        short8_t xv[4];
#pragma unroll
        for (int u = 0; u < 4; ++u) ev[u] = epk[k + u];
#pragma unroll
        for (int u = 0; u < 4; ++u)
            xv[u] = *reinterpret_cast<const short8_t*>(tc + (long)ev[u].x * 64);
#pragma unroll
        for (int u = 0; u < 4; ++u) {
            float v = __int_as_float(ev[u].y);
#pragma unroll
            for (int j = 0; j < 8; ++j) a[j] = fmaf(v, bf2f(xv[u][j]), a[j]);
        }
    }
    for (; k < end; ++k) {
        int2 e0 = epk[k];
        short8_t x0 = *reinterpret_cast<const short8_t*>(tc + (long)e0.x * 64);
        float v = __int_as_float(e0.y);
#pragma unroll
        for (int j = 0; j < 8; ++j) a[j] = fmaf(v, bf2f(x0[j]), a[j]);
    }
    if (l < 4) {
        long o = (long)node * 32 + l * 8;
        *reinterpret_cast<float4*>(outf + o) = make_float4(a[0], a[1], a[2], a[3]);
        *reinterpret_cast<float4*>(outf + o + 4) = make_float4(a[4], a[5], a[6], a[7]);
    } else {
        long o = (long)node * 32 + (l - 4) * 8;
        short8_t s;
#pragma unroll
        for (int j = 0; j < 8; ++j) s[j] = f2bf(a[j]);
        *reinterpret_cast<short8_t*>(outb + o) = s;
    }
}

// ---------------- fused GEMM + bias + sigmoid (t2 folded) ----------------
// out = sigmoid(t0@(W0-W2) + t1@W1 + U@(2*W2) + b); t0,U fp32; t1 bf16.

template <int DIN, int DOUT, bool MIRROR>
__global__ __launch_bounds__(256) void gemm3_kernel(
        const float* __restrict__ t0, const short* __restrict__ t1b,
        const float* __restrict__ t2, const float* __restrict__ W,
        const float* __restrict__ b, float* __restrict__ out,
        short* __restrict__ outb, int n) {
    constexpr int CPT = 8;
    constexpr int RPT = 4;
    constexpr int TPR = DOUT / CPT;
    constexpr int TROWS = 256 / TPR;
    constexpr int RPB = TROWS * RPT;
    constexpr int P = DIN * DOUT;

    __shared__ float sW[3 * P];
    __shared__ float sb[DOUT];
    for (int i = threadIdx.x; i < P; i += 256) {
        float w0 = W[i], w1 = W[P + i], w2 = W[2 * P + i];
        sW[i] = w0 - w2;
        sW[P + i] = w1;
        sW[2 * P + i] = 2.0f * w2;
    }
    if (threadIdx.x < DOUT) sb[threadIdx.x] = b[threadIdx.x];
    __syncthreads();

    const int oc = (threadIdx.x % TPR) * CPT;
    const int rt = threadIdx.x / TPR;
    const int rbase = blockIdx.x * RPB + rt;

    int rows[RPT];
#pragma unroll
    for (int i = 0; i < RPT; ++i) {
        int r = rbase + i * TROWS;
        rows[i] = (r < n) ? r : (n - 1);
    }

    float acc[RPT][CPT];
#pragma unroll
    for (int i = 0; i < RPT; ++i)
#pragma unroll
        for (int j = 0; j < CPT; ++j) acc[i][j] = 0.0f;

    for (int d4 = 0; d4 < DIN; d4 += 4) {
        float4 av0[RPT], av2[RPT];
        short4_t av1[RPT];
#pragma unroll
        for (int i = 0; i < RPT; ++i) {
            av0[i] = *reinterpret_cast<const float4*>(t0 + (long)rows[i] * DIN + d4);
            av1[i] = *reinterpret_cast<const short4_t*>(t1b + (long)rows[i] * DIN + d4);
            av2[i] = *reinterpret_cast<const float4*>(t2 + (long)rows[i] * DIN + d4);
        }
#pragma unroll
        for (int dd = 0; dd < 4; ++dd) {
            int d = d4 + dd;
            float4 w0[2], w1[2], w2[2];
            {
                const float4* wp0 = reinterpret_cast<const float4*>(sW + d * DOUT + oc);
                const float4* wp1 = reinterpret_cast<const float4*>(sW + P + d * DOUT + oc);
                const float4* wp2 = reinterpret_cast<const float4*>(sW + 2 * P + d * DOUT + oc);
                w0[0] = wp0[0]; w0[1] = wp0[1];
                w1[0] = wp1[0]; w1[1] = wp1[1];
                w2[0] = wp2[0]; w2[1] = wp2[1];
            }
            const float* wf0 = reinterpret_cast<const float*>(&w0[0]);
            const float* wf1 = reinterpret_cast<const float*>(&w1[0]);
            const float* wf2 = reinterpret_cast<const float*>(&w2[0]);
#pragma unroll
            for (int i = 0; i < RPT; ++i) {
                float a0 = reinterpret_cast<const float*>(&av0[i])[dd];
                float a1 = bf2f(av1[i][dd]);
                float a2 = reinterpret_cast<const float*>(&av2[i])[dd];
#pragma unroll
                for (int j = 0; j < CPT; ++j) {
                    acc[i][j] = fmaf(a0, wf0[j], acc[i][j]);
                    acc[i][j] = fmaf(a1, wf1[j], acc[i][j]);
                    acc[i][j] = fmaf(a2, wf2[j], acc[i][j]);
                }
            }
        }
    }

#pragma unroll
    for (int i = 0; i < RPT; ++i) {
        int r = rbase + i * TROWS;
        if (r >= n) continue;
        float res[CPT];
#pragma unroll
        for (int j = 0; j < CPT; ++j) {
            float z = acc[i][j] + sb[oc + j];
            res[j] = 1.0f / (1.0f + expf(-z));
        }
        long o = (long)r * DOUT + oc;
        float4* po = reinterpret_cast<float4*>(out + o);
        po[0] = make_float4(res[0], res[1], res[2], res[3]);
        po[1] = make_float4(res[4], res[5], res[6], res[7]);
        if (MIRROR) {
            short8_t s;
#pragma unroll
            for (int j = 0; j < CPT; ++j) s[j] = f2bf(res[j]);
            *reinterpret_cast<short8_t*>(outb + o) = s;
        }
    }
}

// ---------------- multi-output GEMM for commute-form layer 3 ----------------
// P12b[n][64] = [h@W1 | h@W2] (bf16), S = h@(W0-W2) + b (fp32 [n][32])

template <int DIN, int DOUT>
__global__ __launch_bounds__(256) void gemm_multi_kernel(
        const float* __restrict__ h, const float* __restrict__ W,
        const float* __restrict__ b, short* __restrict__ P12b,
        float* __restrict__ S, int n) {
    constexpr int CPT = 8;
    constexpr int RPT = 2;
    constexpr int TPR = DOUT / CPT;   // 4
    constexpr int TROWS = 256 / TPR;  // 64
    constexpr int RPB = TROWS * RPT;  // 128
    constexpr int P = DIN * DOUT;

    __shared__ float sW[3 * P];
    __shared__ float sb[DOUT];
    for (int i = threadIdx.x; i < P; i += 256) {
        float w0 = W[i], w1 = W[P + i], w2 = W[2 * P + i];
        sW[i] = w0 - w2;     // S plane
        sW[P + i] = w1;      // P1 plane
        sW[2 * P + i] = w2;  // P2 plane
    }
    if (threadIdx.x < DOUT) sb[threadIdx.x] = b[threadIdx.x];
    __syncthreads();

    const int oc = (threadIdx.x % TPR) * CPT;
    const int rt = threadIdx.x / TPR;
    const int rbase = blockIdx.x * RPB + rt;

    int rows[RPT];
#pragma unroll
    for (int i = 0; i < RPT; ++i) {
        int r = rbase + i * TROWS;
        rows[i] = (r < n) ? r : (n - 1);
    }

    float acc[RPT][3][CPT];
#pragma unroll
    for (int i = 0; i < RPT; ++i)
#pragma unroll
        for (int tt = 0; tt < 3; ++tt)
#pragma unroll
            for (int j = 0; j < CPT; ++j) acc[i][tt][j] = 0.0f;

    for (int d4 = 0; d4 < DIN; d4 += 4) {
        float4 av[RPT];
#pragma unroll
        for (int i = 0; i < RPT; ++i)
            av[i] = *reinterpret_cast<const float4*>(h + (long)rows[i] * DIN + d4);
#pragma unroll
        for (int dd = 0; dd < 4; ++dd) {
            int d = d4 + dd;
            float4 w[3][2];
#pragma unroll
            for (int tt = 0; tt < 3; ++tt) {
                const float4* wp = reinterpret_cast<const float4*>(sW + tt * P + d * DOUT + oc);
                w[tt][0] = wp[0];
                w[tt][1] = wp[1];
            }
#pragma unroll
            for (int i = 0; i < RPT; ++i) {
                float a = reinterpret_cast<const float*>(&av[i])[dd];
#pragma unroll
                for (int tt = 0; tt < 3; ++tt) {
                    const float* wf = reinterpret_cast<const float*>(&w[tt][0]);
#pragma unroll
                    for (int j = 0; j < CPT; ++j)
                        acc[i][tt][j] = fmaf(a, wf[j], acc[i][tt][j]);
                }
            }
        }
    }

#pragma unroll
    for (int i = 0; i < RPT; ++i) {
        int r = rbase + i * TROWS;
        if (r >= n) continue;
        long o64 = (long)r * 64 + oc;
        long o32 = (long)r * 32 + oc;
        short8_t s1, s2;
#pragma unroll
        for (int j = 0; j < CPT; ++j) {
            s1[j] = f2bf(acc[i][1][j]);
            s2[j] = f2bf(acc[i][2][j]);
        }
        *reinterpret_cast<short8_t*>(P12b + o64) = s1;       // P1 in cols 0-31
        *reinterpret_cast<short8_t*>(P12b + o64 + 32) = s2;  // P2 in cols 32-63
        float4* ps = reinterpret_cast<float4*>(S + o32);
        ps[0] = make_float4(acc[i][0][0] + sb[oc], acc[i][0][1] + sb[oc + 1],
                            acc[i][0][2] + sb[oc + 2], acc[i][0][3] + sb[oc + 3]);
        ps[1] = make_float4(acc[i][0][4] + sb[oc + 4], acc[i][0][5] + sb[oc + 5],
                            acc[i][0][6] + sb[oc + 6], acc[i][0][7] + sb[oc + 7]);
    }
}

// out = sigmoid(S + Q1 + 2*Q3), fp32 + bf16 mirror
__global__ __launch_bounds__(256) void ewcomb_kernel(
        const float4* __restrict__ S, const float4* __restrict__ Q1,
        const float4* __restrict__ Q3, float4* __restrict__ out,
        short* __restrict__ outb, long n4) {
    long i = (long)blockIdx.x * 256 + threadIdx.x;
    if (i >= n4) return;
    float4 s = S[i], q1 = Q1[i], q3 = Q3[i];
    float4 r;
    r.x = 1.0f / (1.0f + expf(-(s.x + q1.x + 2.f * q3.x)));
    r.y = 1.0f / (1.0f + expf(-(s.y + q1.y + 2.f * q3.y)));
    r.z = 1.0f / (1.0f + expf(-(s.z + q1.z + 2.f * q3.z)));
    r.w = 1.0f / (1.0f + expf(-(s.w + q1.w + 2.f * q3.w)));
    out[i] = r;
    short4_t sb4;
    sb4[0] = f2bf(r.x); sb4[1] = f2bf(r.y); sb4[2] = f2bf(r.z); sb4[3] = f2bf(r.w);
    *reinterpret_cast<short4_t*>(outb + i * 4) = sb4;
}

// ---------------- host side ----------------

static inline int ceil_div_l(long a, long b) { return (int)((a + b - 1) / b); }

extern "C" void kernel_launch(void* const* d_in, const int* in_sizes, int n_in,
                              void* d_out, int out_size, void* d_ws, size_t ws_size,
                              hipStream_t stream) {
    const float* x  = (const float*)d_in[0];
    const int*   ei = (const int*)d_in[1];
    const float* ew = (const float*)d_in[2];
    const float* W1 = (const float*)d_in[3];  const float* b1 = (const float*)d_in[4];
    const float* W2 = (const float*)d_in[5];  const float* b2 = (const float*)d_in[6];
    const float* W3 = (const float*)d_in[7];  const float* b3 = (const float*)d_in[8];
    const float* W4 = (const float*)d_in[9];  const float* b4 = (const float*)d_in[10];

    const int E = in_sizes[2];          // 1,600,000
    const int n = in_sizes[0] / 64;     // 100,000
    const int* row = ei;
    const int* col = ei + E;
    const int P = (n + NPP - 1) / NPP;  // 391 (<= 512)

    // workspace carve-up (256B aligned)
    char* ws = (char*)d_ws;
    size_t off = 0;
    auto alloc = [&](size_t bytes) -> void* {
        void* p = ws + off;
        off += (bytes + 255) & ~(size_t)255;
        return p;
    };
    int*   pcnt = (int*)alloc(2 * 512 * sizeof(int));   // pcnt | rcnt
    int*   rcnt = pcnt + 512;
    int*   pofs = (int*)alloc((512 + 1) * sizeof(int));
    int*   pcur = (int*)alloc(512 * sizeof(int));
    int*   rofs = (int*)alloc((512 + 1) * sizeof(int));
    int*   rcur = (int*)alloc(512 * sizeof(int));
    float* dinv = (float*)alloc((size_t)n * sizeof(float));
    int*   ofs  = (int*)alloc((size_t)(n + 1) * sizeof(int));
    int2*  bufC = (int2*)alloc((size_t)E * sizeof(int2));
    int2*  bufR = (int2*)alloc((size_t)E * sizeof(int2));
    int2*  epk  = (int2*)alloc((size_t)E * sizeof(int2));
    float* X    = (float*)alloc((size_t)n * 64 * sizeof(float));
    float* Z    = (float*)alloc((size_t)n * 64 * sizeof(float));
    short* T1b  = (short*)alloc((size_t)n * 64 * sizeof(short));
    short* mX   = (short*)alloc((size_t)n * 64 * sizeof(short));
    if (off > ws_size) return;  // fail loudly (validation) rather than corrupt

    const int eb = ceil_div_l(E, CHUNK);  // 196

    // bf16 copy of x for layer-1 gathers
    f2b_kernel<<<ceil_div_l((long)n * 16, 256), 256, 0, stream>>>(x, mX, (long)n * 64);

    // partition-based CSR build
    hipMemsetAsync(pcnt, 0, 2 * 512 * sizeof(int), stream);
    part_count_kernel<<<eb, 256, 0, stream>>>(row, col, pcnt, rcnt, P, E);
    part_scan_kernel<<<1, 512, 0, stream>>>(pcnt, rcnt, pofs, pcur, rofs, rcur,
                                            ofs, P, n, E);
    part_scatter_kernel<<<eb, 256, 0, stream>>>(row, col, ew, pcur, rcur,
                                                bufC, bufR, P, E);
    dinv_kernel<<<P, 256, 0, stream>>>(bufR, rofs, dinv, n);
    fine_csr_kernel<<<P, 256, 0, stream>>>(bufC, pofs, dinv, ofs, epk, n);

    const int ab64 = ceil_div_l((long)n * 8, 256);
    const int ab32 = ceil_div_l((long)n * 4, 256);

    // Layer 1 (h = x): t1 -> T1b(bf16), U -> Z, out -> X + mirror mX
    agg_kernel<64, true><<<ab64, 256, 0, stream>>>(ofs, epk, mX, nullptr, T1b, n);
    agg_kernel<64, false><<<ab64, 256, 0, stream>>>(ofs, epk, T1b, Z, nullptr, n);
    gemm3_kernel<64, 64, true><<<ceil_div_l(n, 128), 256, 0, stream>>>(
        x, T1b, Z, W1, b1, X, mX, n);

    // Layer 2
    agg_kernel<64, true><<<ab64, 256, 0, stream>>>(ofs, epk, mX, nullptr, T1b, n);
    agg_kernel<64, false><<<ab64, 256, 0, stream>>>(ofs, epk, T1b, Z, nullptr, n);
    gemm3_kernel<64, 64, true><<<ceil_div_l(n, 128), 256, 0, stream>>>(
        X, T1b, Z, W2, b2, X, mX, n);

    // Layer 3 (64 -> 32), commute form: props in 32-dim, Q1/Q2 fused.
    // P1=h@W1, P2=h@W2 (bf16, packed), S=h@(W0-W2)+b
    // out = sigma(S + L@P1 + 2*L@(L@P2))
    {
        short* P12b = T1b;                 // n x 64 bf16: [P1 | P2]
        float* S    = Z;                   // n x 32 f32
        float* Q1   = Z + (size_t)n * 32;  // n x 32 f32
        short* Q2b  = mX;                  // n x 32 bf16 (h2 mirror dead)
        float* Q3   = X;                   // n x 32 f32 (h3 low half dead after gemm_multi? no - keep reading below)
        float* h4   = X + (size_t)n * 32;  // n x 32 f32
        gemm_multi_kernel<64, 32><<<ceil_div_l(n, 128), 256, 0, stream>>>(
            X, W3, b3, P12b, S, n);
        // NOTE: X (h3) is dead after gemm_multi; reuse its low half for Q3.
        agg_dual_kernel<<<ab64, 256, 0, stream>>>(ofs, epk, P12b, Q1, Q2b, n);
        agg_kernel<32, false><<<ab32, 256, 0, stream>>>(ofs, epk, Q2b, Q3, nullptr, n);
        long n4 = (long)n * 8;  // n*32/4
        ewcomb_kernel<<<ceil_div_l(n4, 256), 256, 0, stream>>>(
            (const float4*)S, (const float4*)Q1, (const float4*)Q3,
            (float4*)h4, mX /* h4 bf16 mirror */, n4);
    }

    // Layer 4 (32 -> 16): h4 = X + n*32 (fp32), bf16 mirror in mX[0:n*32]
    agg_kernel<32, true><<<ab32, 256, 0, stream>>>(ofs, epk, mX, nullptr, T1b, n);
    agg_kernel<32, false><<<ab32, 256, 0, stream>>>(ofs, epk, T1b, Z, nullptr, n);
    gemm3_kernel<32, 16, false><<<ceil_div_l(n, 512), 256, 0, stream>>>(
        X + (size_t)n * 32, T1b, Z, W4, b4, (float*)d_out, nullptr, n);
}

// Round 7
// 493.704 us; speedup vs baseline: 20.3750x; 1.0509x over previous
//
#include <hip/hip_runtime.h>
#include <math.h>

// ChebNet: 4 layers of ChebConv(K=3) + sigmoid.
// norm = -D^{-1/2} A D^{-1/2} (self loops removed)
// per layer: t1 = L@h ; U = L@t1 ; out = sigmoid(h@(W0-W2) + t1@W1 + U@(2*W2) + b)
//
// R1: atomic scatter -> CSR gather; 10.06ms -> 1.28ms
// R2: register-tiled gemm3, fused CSR build; -> 0.949ms
// R3: packed edges, 4-edge unroll, layer-3 commute form; -> 0.823ms
// R4: bf16 gathers, t2 folded into weights; -> 0.660ms
// R5: two-level partition CSR build (LDS histograms); -> 0.519ms
// R6: stored per-block counts + column scans -> ZERO global atomics in build,
//     CHUNK 8192->2048 (occupancy 7%->~40%), bf16-only features, ewcomb fused
//     into final layer-3 agg, bufR packed to 4B.

typedef __attribute__((ext_vector_type(8))) short short8_t;
typedef __attribute__((ext_vector_type(4))) short short4_t;

#define NPP 256          // nodes per partition
#define CHUNK 2048       // edges per block in count/scatter passes

__device__ __forceinline__ float bf2f(short s) {
    return __int_as_float(((int)(unsigned short)s) << 16);
}
__device__ __forceinline__ short f2bf(float f) {  // round-to-nearest-even
    unsigned u = __float_as_uint(f);
    return (short)((u + 0x7FFFu + ((u >> 16) & 1u)) >> 16);
}

// ---------------- fp32 -> bf16 convert ----------------

__global__ __launch_bounds__(256) void f2b_kernel(
        const float* __restrict__ in, short* __restrict__ out, long m) {
    long i = ((long)blockIdx.x * 256 + threadIdx.x) * 4;
    if (i >= m) return;
    float4 v = *reinterpret_cast<const float4*>(in + i);
    short4_t s;
    s[0] = f2bf(v.x); s[1] = f2bf(v.y); s[2] = f2bf(v.z); s[3] = f2bf(v.w);
    *reinterpret_cast<short4_t*>(out + i) = s;
}

// ---------------- pass 1: per-chunk partition counts (stored) ----------------

__global__ __launch_bounds__(256) void count_kernel(
        const int* __restrict__ row, const int* __restrict__ col,
        int* __restrict__ cntC, int* __restrict__ cntR, int P, int E) {
    __shared__ int hc[2][512], hr[2][512];
    for (int i = threadIdx.x; i < P; i += 256) {
        hc[0][i] = 0; hc[1][i] = 0; hr[0][i] = 0; hr[1][i] = 0;
    }
    __syncthreads();
    int cp = threadIdx.x & 1;
    int base = blockIdx.x * CHUNK;
    int lim = min(E, base + CHUNK);
    for (int e = base + threadIdx.x; e < lim; e += 256) {
        atomicAdd(&hc[cp][col[e] >> 8], 1);
        atomicAdd(&hr[cp][row[e] >> 8], 1);
    }
    __syncthreads();
    long o = (long)blockIdx.x * P;
    for (int i = threadIdx.x; i < P; i += 256) {
        cntC[o + i] = hc[0][i] + hc[1][i];
        cntR[o + i] = hr[0][i] + hr[1][i];
    }
}

// ---------------- pass 2: per-partition column scan (in-place) ----------------
// cnt[b][p] becomes exclusive prefix over blocks; ptot[p] = partition total.

__global__ __launch_bounds__(256) void colscan_kernel(
        int* __restrict__ cntC, int* __restrict__ cntR,
        int* __restrict__ ptotC, int* __restrict__ ptotR, int P, int B) {
    int bid = blockIdx.x;
    int* m; int* ptot; int p;
    if (bid < P) { m = cntC; ptot = ptotC; p = bid; }
    else         { m = cntR; ptot = ptotR; p = bid - P; }
    __shared__ int sh[256];
    int run = 0;
    for (int b0 = 0; b0 < B; b0 += 256) {
        int b = b0 + threadIdx.x;
        int v = (b < B) ? m[(long)b * P + p] : 0;
        sh[threadIdx.x] = v;
        __syncthreads();
        for (int o = 1; o < 256; o <<= 1) {
            int t = (threadIdx.x >= o) ? sh[threadIdx.x - o] : 0;
            __syncthreads();
            sh[threadIdx.x] += t;
            __syncthreads();
        }
        if (b < B) m[(long)b * P + p] = run + sh[threadIdx.x] - v;
        run += sh[255];
        __syncthreads();
    }
    if (threadIdx.x == 0) ptot[p] = run;
}

// ---------------- pass 3: scan partition totals ----------------

__global__ __launch_bounds__(512) void pscan_kernel(
        const int* __restrict__ ptotC, const int* __restrict__ ptotR,
        int* __restrict__ pofsC, int* __restrict__ pofsR,
        int* __restrict__ ofs, int P, int n, int E) {
    __shared__ int sh[512];
    int tid = threadIdx.x;
    int v = (tid < P) ? ptotC[tid] : 0;
    sh[tid] = v;
    __syncthreads();
    for (int o = 1; o < 512; o <<= 1) {
        int t = (tid >= o) ? sh[tid - o] : 0;
        __syncthreads();
        sh[tid] += t;
        __syncthreads();
    }
    if (tid < P) pofsC[tid] = sh[tid] - v;
    if (tid == 0) pofsC[P] = E;
    __syncthreads();
    v = (tid < P) ? ptotR[tid] : 0;
    sh[tid] = v;
    __syncthreads();
    for (int o = 1; o < 512; o <<= 1) {
        int t = (tid >= o) ? sh[tid - o] : 0;
        __syncthreads();
        sh[tid] += t;
        __syncthreads();
    }
    if (tid < P) pofsR[tid] = sh[tid] - v;
    if (tid == 0) { pofsR[P] = E; ofs[n] = E; }
}

// ---------------- pass 4: scatter into buckets (no global atomics) ----------------
// bufC: (finec<<24 | row, w_bits)   bufR: finer<<24 | (w_bits>>8)

__global__ __launch_bounds__(256) void scatter_kernel(
        const int* __restrict__ row, const int* __restrict__ col,
        const float* __restrict__ ew,
        const int* __restrict__ cntC, const int* __restrict__ cntR,
        const int* __restrict__ pofsC, const int* __restrict__ pofsR,
        int2* __restrict__ bufC, unsigned* __restrict__ bufR, int P, int E) {
    __shared__ int hc[512], hr[512];
    long o = (long)blockIdx.x * P;
    for (int i = threadIdx.x; i < P; i += 256) {
        hc[i] = pofsC[i] + cntC[o + i];
        hr[i] = pofsR[i] + cntR[o + i];
    }
    __syncthreads();
    int base = blockIdx.x * CHUNK;
    int lim = min(E, base + CHUNK);
    for (int e = base + threadIdx.x; e < lim; e += 256) {
        int r = row[e], c = col[e];
        float w = (r == c) ? 0.0f : ew[e];
        unsigned wb = __float_as_uint(w);
        int pc = atomicAdd(&hc[c >> 8], 1);
        bufC[pc] = make_int2((int)(((unsigned)(c & 255) << 24) | (unsigned)r), (int)wb);
        int pr = atomicAdd(&hr[r >> 8], 1);
        bufR[pr] = ((unsigned)(r & 255) << 24) | (wb >> 8);
    }
}

// ---------------- degree accumulate -> dinv ----------------

__global__ __launch_bounds__(256) void dinv_kernel(
        const unsigned* __restrict__ bufR, const int* __restrict__ rofs,
        float* __restrict__ dinv, int n) {
    int p = blockIdx.x;
    __shared__ float s[NPP];
    s[threadIdx.x] = 0.0f;
    __syncthreads();
    int beg = rofs[p], end = rofs[p + 1];
    for (int k = beg + threadIdx.x; k < end; k += 256) {
        unsigned u = bufR[k];
        atomicAdd(&s[u >> 24], __uint_as_float((u & 0xFFFFFFu) << 8));
    }
    __syncthreads();
    int node = (p << 8) + threadIdx.x;
    if (node < n) {
        float d = s[threadIdx.x];
        dinv[node] = d > 0.0f ? rsqrtf(d) : 0.0f;
    }
}

// ---------------- fine CSR within each col partition + norm ----------------

__global__ __launch_bounds__(256) void fine_csr_kernel(
        const int2* __restrict__ bufC, const int* __restrict__ pofs,
        const float* __restrict__ dinv, int* __restrict__ ofs,
        int2* __restrict__ epk, int n) {
    int p = blockIdx.x;
    int tid = threadIdx.x;
    __shared__ int hist[NPP];
    __shared__ int sc[NPP];
    __shared__ float dc[NPP];
    hist[tid] = 0;
    int node = (p << 8) + tid;
    dc[tid] = (node < n) ? dinv[node] : 0.0f;
    __syncthreads();
    int beg = pofs[p], end = pofs[p + 1];
    for (int k = beg + tid; k < end; k += 256)
        atomicAdd(&hist[((unsigned)bufC[k].x) >> 24], 1);
    __syncthreads();
    int v = hist[tid];
    sc[tid] = v;
    __syncthreads();
    for (int o = 1; o < 256; o <<= 1) {
        int t = (tid >= o) ? sc[tid - o] : 0;
        __syncthreads();
        sc[tid] += t;
        __syncthreads();
    }
    int mybase = beg + sc[tid] - v;  // exclusive
    if (node < n) ofs[node] = mybase;
    hist[tid] = mybase;  // becomes cursor
    __syncthreads();
    for (int k = beg + tid; k < end; k += 256) {
        int2 ed = bufC[k];
        unsigned key = (unsigned)ed.x;
        int fc = key >> 24;
        int r = (int)(key & 0xFFFFFFu);
        float w = __int_as_float(ed.y);
        float nrm = -dinv[r] * w * dc[fc];
        int pos = atomicAdd(&hist[fc], 1);
        epk[pos] = make_int2(r, __float_as_int(nrm));
    }
}

// ---------------- aggregation (bf16 gather, fp32 accumulate, bf16 out) ----------------

template <int D>
__global__ __launch_bounds__(256) void agg_kernel(
        const int* __restrict__ ofs, const int2* __restrict__ epk,
        const short* __restrict__ tb, short* __restrict__ outb, int n) {
    constexpr int LPN = D / 8;
    int idx = blockIdx.x * 256 + threadIdx.x;
    int node = idx / LPN;
    int l = idx % LPN;
    if (node >= n) return;
    int beg = ofs[node], end = ofs[node + 1];
    float a[8] = {0.f, 0.f, 0.f, 0.f, 0.f, 0.f, 0.f, 0.f};
    const short* tc = tb + l * 8;
    int k = beg;
    for (; k + 4 <= end; k += 4) {
        int2 ev[4];
        short8_t xv[4];
#pragma unroll
        for (int u = 0; u < 4; ++u) ev[u] = epk[k + u];
#pragma unroll
        for (int u = 0; u < 4; ++u)
            xv[u] = *reinterpret_cast<const short8_t*>(tc + (long)ev[u].x * D);
#pragma unroll
        for (int u = 0; u < 4; ++u) {
            float v = __int_as_float(ev[u].y);
#pragma unroll
            for (int j = 0; j < 8; ++j) a[j] = fmaf(v, bf2f(xv[u][j]), a[j]);
        }
    }
    for (; k < end; ++k) {
        int2 e0 = epk[k];
        short8_t x0 = *reinterpret_cast<const short8_t*>(tc + (long)e0.x * D);
        float v = __int_as_float(e0.y);
#pragma unroll
        for (int j = 0; j < 8; ++j) a[j] = fmaf(v, bf2f(x0[j]), a[j]);
    }
    short8_t s;
#pragma unroll
    for (int j = 0; j < 8; ++j) s[j] = f2bf(a[j]);
    *reinterpret_cast<short8_t*>(outb + (long)node * D + l * 8) = s;
}

// Dual agg for layer 3: tb [n][64] = [P1|P2] bf16; lanes 0-3 -> Q1b, 4-7 -> Q2b.

__global__ __launch_bounds__(256) void agg_dual_kernel(
        const int* __restrict__ ofs, const int2* __restrict__ epk,
        const short* __restrict__ tb, short* __restrict__ Q1b,
        short* __restrict__ Q2b, int n) {
    int idx = blockIdx.x * 256 + threadIdx.x;
    int node = idx >> 3;
    int l = idx & 7;
    if (node >= n) return;
    int beg = ofs[node], end = ofs[node + 1];
    float a[8] = {0.f, 0.f, 0.f, 0.f, 0.f, 0.f, 0.f, 0.f};
    const short* tc = tb + l * 8;
    int k = beg;
    for (; k + 4 <= end; k += 4) {
        int2 ev[4];
        short8_t xv[4];
#pragma unroll
        for (int u = 0; u < 4; ++u) ev[u] = epk[k + u];
#pragma unroll
        for (int u = 0; u < 4; ++u)
            xv[u] = *reinterpret_cast<const short8_t*>(tc + (long)ev[u].x * 64);
#pragma unroll
        for (int u = 0; u < 4; ++u) {
            float v = __int_as_float(ev[u].y);
#pragma unroll
            for (int j = 0; j < 8; ++j) a[j] = fmaf(v, bf2f(xv[u][j]), a[j]);
        }
    }
    for (; k < end; ++k) {
        int2 e0 = epk[k];
        short8_t x0 = *reinterpret_cast<const short8_t*>(tc + (long)e0.x * 64);
        float v = __int_as_float(e0.y);
#pragma unroll
        for (int j = 0; j < 8; ++j) a[j] = fmaf(v, bf2f(x0[j]), a[j]);
    }
    short* ob = (l < 4) ? Q1b : Q2b;
    long o = (long)node * 32 + (l & 3) * 8;
    short8_t s;
#pragma unroll
    for (int j = 0; j < 8; ++j) s[j] = f2bf(a[j]);
    *reinterpret_cast<short8_t*>(ob + o) = s;
}

// Final layer-3 agg: acc = L@Q2 gather; out = sigmoid(S + Q1 + 2*acc) (bf16).

__global__ __launch_bounds__(256) void agg_fin_kernel(
        const int* __restrict__ ofs, const int2* __restrict__ epk,
        const short* __restrict__ Q2b, const float* __restrict__ S,
        const short* __restrict__ Q1b, short* __restrict__ outb, int n) {
    int idx = blockIdx.x * 256 + threadIdx.x;
    int node = idx >> 2;
    int l = idx & 3;
    if (node >= n) return;
    int beg = ofs[node], end = ofs[node + 1];
    float a[8] = {0.f, 0.f, 0.f, 0.f, 0.f, 0.f, 0.f, 0.f};
    const short* tc = Q2b + l * 8;
    int k = beg;
    for (; k + 4 <= end; k += 4) {
        int2 ev[4];
        short8_t xv[4];
#pragma unroll
        for (int u = 0; u < 4; ++u) ev[u] = epk[k + u];
#pragma unroll
        for (int u = 0; u < 4; ++u)
            xv[u] = *reinterpret_cast<const short8_t*>(tc + (long)ev[u].x * 32);
#pragma unroll
        for (int u = 0; u < 4; ++u) {
            float v = __int_as_float(ev[u].y);
#pragma unroll
            for (int j = 0; j < 8; ++j) a[j] = fmaf(v, bf2f(xv[u][j]), a[j]);
        }
    }
    for (; k < end; ++k) {
        int2 e0 = epk[k];
        short8_t x0 = *reinterpret_cast<const short8_t*>(tc + (long)e0.x * 32);
        float v = __int_as_float(e0.y);
#pragma unroll
        for (int j = 0; j < 8; ++j) a[j] = fmaf(v, bf2f(x0[j]), a[j]);
    }
    long o = (long)node * 32 + l * 8;
    float4 s0 = *reinterpret_cast<const float4*>(S + o);
    float4 s1 = *reinterpret_cast<const float4*>(S + o + 4);
    short8_t q1 = *reinterpret_cast<const short8_t*>(Q1b + o);
    const float* sf = reinterpret_cast<const float*>(&s0);  // s0,s1 contiguous? no
    float sv[8] = {s0.x, s0.y, s0.z, s0.w, s1.x, s1.y, s1.z, s1.w};
    short8_t r;
#pragma unroll
    for (int j = 0; j < 8; ++j) {
        float z = sv[j] + bf2f(q1[j]) + 2.0f * a[j];
        r[j] = f2bf(1.0f / (1.0f + expf(-z)));
    }
    (void)sf;
    *reinterpret_cast<short8_t*>(outb + o) = r;
}

// ---------------- fused GEMM + bias + sigmoid (t2 folded, all-bf16 in) ----------------
// out = sigmoid(t0@(W0-W2) + t1@W1 + U@(2*W2) + b)

template <int DIN, int DOUT, bool F32OUT>
__global__ __launch_bounds__(256) void gemm3_kernel(
        const short* __restrict__ t0b, const short* __restrict__ t1b,
        const short* __restrict__ t2b, const float* __restrict__ W,
        const float* __restrict__ b, float* __restrict__ outf,
        short* __restrict__ outb, int n) {
    constexpr int CPT = 8;
    constexpr int RPT = 4;
    constexpr int TPR = DOUT / CPT;
    constexpr int TROWS = 256 / TPR;
    constexpr int RPB = TROWS * RPT;
    constexpr int P = DIN * DOUT;

    __shared__ float sW[3 * P];
    __shared__ float sb[DOUT];
    for (int i = threadIdx.x; i < P; i += 256) {
        float w0 = W[i], w1 = W[P + i], w2 = W[2 * P + i];
        sW[i] = w0 - w2;
        sW[P + i] = w1;
        sW[2 * P + i] = 2.0f * w2;
    }
    if (threadIdx.x < DOUT) sb[threadIdx.x] = b[threadIdx.x];
    __syncthreads();

    const int oc = (threadIdx.x % TPR) * CPT;
    const int rt = threadIdx.x / TPR;
    const int rbase = blockIdx.x * RPB + rt;

    int rows[RPT];
#pragma unroll
    for (int i = 0; i < RPT; ++i) {
        int r = rbase + i * TROWS;
        rows[i] = (r < n) ? r : (n - 1);
    }

    float acc[RPT][CPT];
#pragma unroll
    for (int i = 0; i < RPT; ++i)
#pragma unroll
        for (int j = 0; j < CPT; ++j) acc[i][j] = 0.0f;

    for (int d4 = 0; d4 < DIN; d4 += 4) {
        short4_t av0[RPT], av1[RPT], av2[RPT];
#pragma unroll
        for (int i = 0; i < RPT; ++i) {
            av0[i] = *reinterpret_cast<const short4_t*>(t0b + (long)rows[i] * DIN + d4);
            av1[i] = *reinterpret_cast<const short4_t*>(t1b + (long)rows[i] * DIN + d4);
            av2[i] = *reinterpret_cast<const short4_t*>(t2b + (long)rows[i] * DIN + d4);
        }
#pragma unroll
        for (int dd = 0; dd < 4; ++dd) {
            int d = d4 + dd;
            float4 w0[2], w1[2], w2[2];
            {
                const float4* wp0 = reinterpret_cast<const float4*>(sW + d * DOUT + oc);
                const float4* wp1 = reinterpret_cast<const float4*>(sW + P + d * DOUT + oc);
                const float4* wp2 = reinterpret_cast<const float4*>(sW + 2 * P + d * DOUT + oc);
                w0[0] = wp0[0]; w0[1] = wp0[1];
                w1[0] = wp1[0]; w1[1] = wp1[1];
                w2[0] = wp2[0]; w2[1] = wp2[1];
            }
            const float* wf0 = reinterpret_cast<const float*>(&w0[0]);
            const float* wf1 = reinterpret_cast<const float*>(&w1[0]);
            const float* wf2 = reinterpret_cast<const float*>(&w2[0]);
#pragma unroll
            for (int i = 0; i < RPT; ++i) {
                float a0 = bf2f(av0[i][dd]);
                float a1 = bf2f(av1[i][dd]);
                float a2 = bf2f(av2[i][dd]);
#pragma unroll
                for (int j = 0; j < CPT; ++j) {
                    acc[i][j] = fmaf(a0, wf0[j], acc[i][j]);
                    acc[i][j] = fmaf(a1, wf1[j], acc[i][j]);
                    acc[i][j] = fmaf(a2, wf2[j], acc[i][j]);
                }
            }
        }
    }

#pragma unroll
    for (int i = 0; i < RPT; ++i) {
        int r = rbase + i * TROWS;
        if (r >= n) continue;
        float res[CPT];
#pragma unroll
        for (int j = 0; j < CPT; ++j) {
            float z = acc[i][j] + sb[oc + j];
            res[j] = 1.0f / (1.0f + expf(-z));
        }
        long o = (long)r * DOUT + oc;
        if (F32OUT) {
            float4* po = reinterpret_cast<float4*>(outf + o);
            po[0] = make_float4(res[0], res[1], res[2], res[3]);
            po[1] = make_float4(res[4], res[5], res[6], res[7]);
        } else {
            short8_t s;
#pragma unroll
            for (int j = 0; j < CPT; ++j) s[j] = f2bf(res[j]);
            *reinterpret_cast<short8_t*>(outb + o) = s;
        }
    }
}

// ---------------- multi-output GEMM for commute-form layer 3 ----------------
// P12b[n][64] = [h@W1 | h@W2] (bf16), S = h@(W0-W2) + b (fp32 [n][32])

template <int DIN, int DOUT>
__global__ __launch_bounds__(256) void gemm_multi_kernel(
        const short* __restrict__ hb, const float* __restrict__ W,
        const float* __restrict__ b, short* __restrict__ P12b,
        float* __restrict__ S, int n) {
    constexpr int CPT = 8;
    constexpr int RPT = 2;
    constexpr int TPR = DOUT / CPT;   // 4
    constexpr int TROWS = 256 / TPR;  // 64
    constexpr int RPB = TROWS * RPT;  // 128
    constexpr int P = DIN * DOUT;

    __shared__ float sW[3 * P];
    __shared__ float sb[DOUT];
    for (int i = threadIdx.x; i < P; i += 256) {
        float w0 = W[i], w1 = W[P + i], w2 = W[2 * P + i];
        sW[i] = w0 - w2;     // S plane
        sW[P + i] = w1;      // P1 plane
        sW[2 * P + i] = w2;  // P2 plane
    }
    if (threadIdx.x < DOUT) sb[threadIdx.x] = b[threadIdx.x];
    __syncthreads();

    const int oc = (threadIdx.x % TPR) * CPT;
    const int rt = threadIdx.x / TPR;
    const int rbase = blockIdx.x * RPB + rt;

    int rows[RPT];
#pragma unroll
    for (int i = 0; i < RPT; ++i) {
        int r = rbase + i * TROWS;
        rows[i] = (r < n) ? r : (n - 1);
    }

    float acc[RPT][3][CPT];
#pragma unroll
    for (int i = 0; i < RPT; ++i)
#pragma unroll
        for (int tt = 0; tt < 3; ++tt)
#pragma unroll
            for (int j = 0; j < CPT; ++j) acc[i][tt][j] = 0.0f;

    for (int d4 = 0; d4 < DIN; d4 += 4) {
        short4_t av[RPT];
#pragma unroll
        for (int i = 0; i < RPT; ++i)
            av[i] = *reinterpret_cast<const short4_t*>(hb + (long)rows[i] * DIN + d4);
#pragma unroll
        for (int dd = 0; dd < 4; ++dd) {
            int d = d4 + dd;
            float4 w[3][2];
#pragma unroll
            for (int tt = 0; tt < 3; ++tt) {
                const float4* wp = reinterpret_cast<const float4*>(sW + tt * P + d * DOUT + oc);
                w[tt][0] = wp[0];
                w[tt][1] = wp[1];
            }
#pragma unroll
            for (int i = 0; i < RPT; ++i) {
                float a = bf2f(av[i][dd]);
#pragma unroll
                for (int tt = 0; tt < 3; ++tt) {
                    const float* wf = reinterpret_cast<const float*>(&w[tt][0]);
#pragma unroll
                    for (int j = 0; j < CPT; ++j)
                        acc[i][tt][j] = fmaf(a, wf[j], acc[i][tt][j]);
                }
            }
        }
    }

#pragma unroll
    for (int i = 0; i < RPT; ++i) {
        int r = rbase + i * TROWS;
        if (r >= n) continue;
        long o64 = (long)r * 64 + oc;
        long o32 = (long)r * 32 + oc;
        short8_t s1, s2;
#pragma unroll
        for (int j = 0; j < CPT; ++j) {
            s1[j] = f2bf(acc[i][1][j]);
            s2[j] = f2bf(acc[i][2][j]);
        }
        *reinterpret_cast<short8_t*>(P12b + o64) = s1;       // P1 in cols 0-31
        *reinterpret_cast<short8_t*>(P12b + o64 + 32) = s2;  // P2 in cols 32-63
        float4* ps = reinterpret_cast<float4*>(S + o32);
        ps[0] = make_float4(acc[i][0][0] + sb[oc], acc[i][0][1] + sb[oc + 1],
                            acc[i][0][2] + sb[oc + 2], acc[i][0][3] + sb[oc + 3]);
        ps[1] = make_float4(acc[i][0][4] + sb[oc + 4], acc[i][0][5] + sb[oc + 5],
                            acc[i][0][6] + sb[oc + 6], acc[i][0][7] + sb[oc + 7]);
    }
}

// ---------------- host side ----------------

static inline int ceil_div_l(long a, long b) { return (int)((a + b - 1) / b); }

extern "C" void kernel_launch(void* const* d_in, const int* in_sizes, int n_in,
                              void* d_out, int out_size, void* d_ws, size_t ws_size,
                              hipStream_t stream) {
    const float* x  = (const float*)d_in[0];
    const int*   ei = (const int*)d_in[1];
    const float* ew = (const float*)d_in[2];
    const float* W1 = (const float*)d_in[3];  const float* b1 = (const float*)d_in[4];
    const float* W2 = (const float*)d_in[5];  const float* b2 = (const float*)d_in[6];
    const float* W3 = (const float*)d_in[7];  const float* b3 = (const float*)d_in[8];
    const float* W4 = (const float*)d_in[9];  const float* b4 = (const float*)d_in[10];

    const int E = in_sizes[2];          // 1,600,000
    const int n = in_sizes[0] / 64;     // 100,000
    const int* row = ei;
    const int* col = ei + E;
    const int P = (n + NPP - 1) / NPP;  // 391 (<= 512)
    const int B = (E + CHUNK - 1) / CHUNK;  // 782

    // workspace carve-up (256B aligned)
    char* ws = (char*)d_ws;
    size_t off = 0;
    auto alloc = [&](size_t bytes) -> void* {
        void* p = ws + off;
        off += (bytes + 255) & ~(size_t)255;
        return p;
    };
    int*      cntC = (int*)alloc((size_t)B * P * sizeof(int));
    int*      cntR = (int*)alloc((size_t)B * P * sizeof(int));
    int*      ptotC = (int*)alloc(512 * sizeof(int));
    int*      ptotR = (int*)alloc(512 * sizeof(int));
    int*      pofsC = (int*)alloc((512 + 1) * sizeof(int));
    int*      pofsR = (int*)alloc((512 + 1) * sizeof(int));
    float*    dinv = (float*)alloc((size_t)n * sizeof(float));
    int*      ofs  = (int*)alloc((size_t)(n + 1) * sizeof(int));
    int2*     bufC = (int2*)alloc((size_t)E * sizeof(int2));
    unsigned* bufR = (unsigned*)alloc((size_t)E * sizeof(unsigned));
    int2*     epk  = (int2*)alloc((size_t)E * sizeof(int2));
    short*    hbA  = (short*)alloc((size_t)n * 64 * sizeof(short));
    short*    hbB  = (short*)alloc((size_t)n * 64 * sizeof(short));
    short*    t1b  = (short*)alloc((size_t)n * 64 * sizeof(short));
    short*    Ub   = (short*)alloc((size_t)n * 64 * sizeof(short));
    float*    S    = (float*)alloc((size_t)n * 32 * sizeof(float));
    if (off > ws_size) return;  // fail loudly (validation) rather than corrupt

    // bf16 copy of x (layer-1 input)
    f2b_kernel<<<ceil_div_l((long)n * 16, 256), 256, 0, stream>>>(x, hbA, (long)n * 64);

    // CSR build: count -> colscan -> pscan -> scatter -> dinv -> fine (0 global atomics)
    count_kernel<<<B, 256, 0, stream>>>(row, col, cntC, cntR, P, E);
    colscan_kernel<<<2 * P, 256, 0, stream>>>(cntC, cntR, ptotC, ptotR, P, B);
    pscan_kernel<<<1, 512, 0, stream>>>(ptotC, ptotR, pofsC, pofsR, ofs, P, n, E);
    scatter_kernel<<<B, 256, 0, stream>>>(row, col, ew, cntC, cntR, pofsC, pofsR,
                                          bufC, bufR, P, E);
    dinv_kernel<<<P, 256, 0, stream>>>(bufR, pofsR, dinv, n);
    fine_csr_kernel<<<P, 256, 0, stream>>>(bufC, pofsC, dinv, ofs, epk, n);

    const int ab64 = ceil_div_l((long)n * 8, 256);
    const int ab32 = ceil_div_l((long)n * 4, 256);

    // Layer 1 (hbA = x): t1b = L@hbA; Ub = L@t1b; hbB = gemm
    agg_kernel<64><<<ab64, 256, 0, stream>>>(ofs, epk, hbA, t1b, n);
    agg_kernel<64><<<ab64, 256, 0, stream>>>(ofs, epk, t1b, Ub, n);
    gemm3_kernel<64, 64, false><<<ceil_div_l(n, 128), 256, 0, stream>>>(
        hbA, t1b, Ub, W1, b1, nullptr, hbB, n);

    // Layer 2: hbA = gemm(hbB, ...)
    agg_kernel<64><<<ab64, 256, 0, stream>>>(ofs, epk, hbB, t1b, n);
    agg_kernel<64><<<ab64, 256, 0, stream>>>(ofs, epk, t1b, Ub, n);
    gemm3_kernel<64, 64, false><<<ceil_div_l(n, 128), 256, 0, stream>>>(
        hbB, t1b, Ub, W2, b2, nullptr, hbA, n);

    // Layer 3 (64 -> 32), commute form, props in 32-dim:
    // P1=h@W1, P2=h@W2 (bf16 packed in t1b), S=h@(W0-W2)+b
    // out = sigma(S + L@P1 + 2*L@(L@P2))  -> hb3 = hbB[0:n*32]
    {
        short* P12b = t1b;
        short* Q1b  = Ub;
        short* Q2b  = Ub + (size_t)n * 32;
        short* hb3  = hbB;
        gemm_multi_kernel<64, 32><<<ceil_div_l(n, 128), 256, 0, stream>>>(
            hbA, W3, b3, P12b, S, n);
        agg_dual_kernel<<<ab64, 256, 0, stream>>>(ofs, epk, P12b, Q1b, Q2b, n);
        agg_fin_kernel<<<ab32, 256, 0, stream>>>(ofs, epk, Q2b, S, Q1b, hb3, n);
    }

    // Layer 4 (32 -> 16): t1b32 = L@hb3; Ub32 = L@t1b32; d_out = gemm (fp32)
    agg_kernel<32><<<ab32, 256, 0, stream>>>(ofs, epk, hbB, t1b, n);
    agg_kernel<32><<<ab32, 256, 0, stream>>>(ofs, epk, t1b, Ub, n);
    gemm3_kernel<32, 16, true><<<ceil_div_l(n, 512), 256, 0, stream>>>(
        hbB, t1b, Ub, W4, b4, (float*)d_out, nullptr, n);
}

// Round 8
// 396.948 us; speedup vs baseline: 25.3415x; 1.2438x over previous
//
#include <hip/hip_runtime.h>
#include <math.h>

// ChebNet: 4 layers of ChebConv(K=3) + sigmoid.
// norm = -D^{-1/2} A D^{-1/2} (self loops removed)
// per layer: t1 = L@h ; U = L@t1 ; out = sigmoid(h@(W0-W2) + t1@W1 + U@(2*W2) + b)
//
// R1: atomic scatter -> CSR gather; 10.06ms -> 1.28ms
// R2: register-tiled gemm3, fused CSR build; -> 0.949ms
// R3: packed edges, 4-edge unroll, layer-3 commute form; -> 0.823ms
// R4: bf16 gathers, t2 folded into weights; -> 0.660ms
// R5: two-level partition CSR build (LDS histograms); -> 0.519ms
// R6: zero-global-atomic CSR build, bf16-only features; -> 0.494ms
// R7: all GEMMs -> MFMA (v_mfma_f32_16x16x32_bf16), weights pre-packed into
//     per-lane B fragments (prep_kernel), zero LDS in gemm kernels.

typedef __attribute__((ext_vector_type(8))) short short8_t;
typedef __attribute__((ext_vector_type(4))) short short4_t;
typedef __attribute__((ext_vector_type(4))) float f32x4;

#define NPP 256          // nodes per partition
#define CHUNK 2048       // edges per block in count/scatter passes

__device__ __forceinline__ float bf2f(short s) {
    return __int_as_float(((int)(unsigned short)s) << 16);
}
__device__ __forceinline__ short f2bf(float f) {  // round-to-nearest-even
    unsigned u = __float_as_uint(f);
    return (short)((u + 0x7FFFu + ((u >> 16) & 1u)) >> 16);
}

// ---------------- fp32 -> bf16 convert ----------------

__global__ __launch_bounds__(256) void f2b_kernel(
        const float* __restrict__ in, short* __restrict__ out, long m) {
    long i = ((long)blockIdx.x * 256 + threadIdx.x) * 4;
    if (i >= m) return;
    float4 v = *reinterpret_cast<const float4*>(in + i);
    short4_t s;
    s[0] = f2bf(v.x); s[1] = f2bf(v.y); s[2] = f2bf(v.z); s[3] = f2bf(v.w);
    *reinterpret_cast<short4_t*>(out + i) = s;
}

// ---------------- weight fragment pre-pack ----------------
// B-fragment layout for mfma_f32_16x16x32_bf16: lane holds B[k][col] with
// col = lane&15, k = (lane>>4)*8 + e. Frag arrays indexed [s][ct][lane].
// wpk1/wpk2: [6][4][64] (K=192: t0|t1|U planes, folded W0-W2 / W1 / 2W2)
// wpkm:      [2][6][64] (K=64; col groups: S=W0-W2, P1=W1, P2=W2)
// wpk4:      [3][1][64] (K=96 over 32-dim inputs)

__global__ __launch_bounds__(256) void prep_kernel(
        const float* __restrict__ W1, const float* __restrict__ W2,
        const float* __restrict__ W3, const float* __restrict__ W4,
        short8_t* __restrict__ wpk1, short8_t* __restrict__ wpk2,
        short8_t* __restrict__ wpkm, short8_t* __restrict__ wpk4) {
    int idx = blockIdx.x * 256 + threadIdx.x;
    if (idx >= 4032) return;
    short8_t out;
    if (idx < 3072) {  // gemm3 packs for W1 / W2 (64->64)
        const float* W = (idx < 1536) ? W1 : W2;
        int f = (idx < 1536) ? idx : idx - 1536;
        int lane = f & 63, ct = (f >> 6) & 3, s = f >> 8;
        int li = lane & 15, lg = lane >> 4;
        int p = s >> 1;
        int col = ct * 16 + li;
#pragma unroll
        for (int e = 0; e < 8; ++e) {
            int k = (s & 1) * 32 + lg * 8 + e;
            int base = k * 64 + col;
            float v = (p == 0) ? W[base] - W[8192 + base]
                    : (p == 1) ? W[4096 + base]
                               : 2.0f * W[8192 + base];
            out[e] = f2bf(v);
        }
        ((idx < 1536) ? wpk1 : wpk2)[f] = out;
    } else if (idx < 3840) {  // gemm_multi pack for W3 (64->3x32)
        int f = idx - 3072;
        int lane = f & 63, q = f >> 6;
        int s = q / 6, ct = q % 6;
        int li = lane & 15, lg = lane >> 4;
        int g = ct >> 1;
        int cl = (ct & 1) * 16 + li;
#pragma unroll
        for (int e = 0; e < 8; ++e) {
            int k = s * 32 + lg * 8 + e;
            int base = k * 32 + cl;
            float v = (g == 0) ? W3[base] - W3[4096 + base]
                    : (g == 1) ? W3[2048 + base]
                               : W3[4096 + base];
            out[e] = f2bf(v);
        }
        wpkm[f] = out;
    } else {  // gemm4 pack for W4 (32->16)
        int f = idx - 3840;
        int lane = f & 63, s = f >> 6;
        int li = lane & 15, lg = lane >> 4;
#pragma unroll
        for (int e = 0; e < 8; ++e) {
            int k = lg * 8 + e;
            int base = k * 16 + li;
            float v = (s == 0) ? W4[base] - W4[1024 + base]
                    : (s == 1) ? W4[512 + base]
                               : 2.0f * W4[1024 + base];
            out[e] = f2bf(v);
        }
        wpk4[f] = out;
    }
}

// ---------------- CSR build (R6, zero global atomics) ----------------

__global__ __launch_bounds__(256) void count_kernel(
        const int* __restrict__ row, const int* __restrict__ col,
        int* __restrict__ cntC, int* __restrict__ cntR, int P, int E) {
    __shared__ int hc[2][512], hr[2][512];
    for (int i = threadIdx.x; i < P; i += 256) {
        hc[0][i] = 0; hc[1][i] = 0; hr[0][i] = 0; hr[1][i] = 0;
    }
    __syncthreads();
    int cp = threadIdx.x & 1;
    int base = blockIdx.x * CHUNK;
    int lim = min(E, base + CHUNK);
    for (int e = base + threadIdx.x; e < lim; e += 256) {
        atomicAdd(&hc[cp][col[e] >> 8], 1);
        atomicAdd(&hr[cp][row[e] >> 8], 1);
    }
    __syncthreads();
    long o = (long)blockIdx.x * P;
    for (int i = threadIdx.x; i < P; i += 256) {
        cntC[o + i] = hc[0][i] + hc[1][i];
        cntR[o + i] = hr[0][i] + hr[1][i];
    }
}

__global__ __launch_bounds__(256) void colscan_kernel(
        int* __restrict__ cntC, int* __restrict__ cntR,
        int* __restrict__ ptotC, int* __restrict__ ptotR, int P, int B) {
    int bid = blockIdx.x;
    int* m; int* ptot; int p;
    if (bid < P) { m = cntC; ptot = ptotC; p = bid; }
    else         { m = cntR; ptot = ptotR; p = bid - P; }
    __shared__ int sh[256];
    int run = 0;
    for (int b0 = 0; b0 < B; b0 += 256) {
        int b = b0 + threadIdx.x;
        int v = (b < B) ? m[(long)b * P + p] : 0;
        sh[threadIdx.x] = v;
        __syncthreads();
        for (int o = 1; o < 256; o <<= 1) {
            int t = (threadIdx.x >= o) ? sh[threadIdx.x - o] : 0;
            __syncthreads();
            sh[threadIdx.x] += t;
            __syncthreads();
        }
        if (b < B) m[(long)b * P + p] = run + sh[threadIdx.x] - v;
        run += sh[255];
        __syncthreads();
    }
    if (threadIdx.x == 0) ptot[p] = run;
}

__global__ __launch_bounds__(512) void pscan_kernel(
        const int* __restrict__ ptotC, const int* __restrict__ ptotR,
        int* __restrict__ pofsC, int* __restrict__ pofsR,
        int* __restrict__ ofs, int P, int n, int E) {
    __shared__ int sh[512];
    int tid = threadIdx.x;
    int v = (tid < P) ? ptotC[tid] : 0;
    sh[tid] = v;
    __syncthreads();
    for (int o = 1; o < 512; o <<= 1) {
        int t = (tid >= o) ? sh[tid - o] : 0;
        __syncthreads();
        sh[tid] += t;
        __syncthreads();
    }
    if (tid < P) pofsC[tid] = sh[tid] - v;
    if (tid == 0) pofsC[P] = E;
    __syncthreads();
    v = (tid < P) ? ptotR[tid] : 0;
    sh[tid] = v;
    __syncthreads();
    for (int o = 1; o < 512; o <<= 1) {
        int t = (tid >= o) ? sh[tid - o] : 0;
        __syncthreads();
        sh[tid] += t;
        __syncthreads();
    }
    if (tid < P) pofsR[tid] = sh[tid] - v;
    if (tid == 0) { pofsR[P] = E; ofs[n] = E; }
}

__global__ __launch_bounds__(256) void scatter_kernel(
        const int* __restrict__ row, const int* __restrict__ col,
        const float* __restrict__ ew,
        const int* __restrict__ cntC, const int* __restrict__ cntR,
        const int* __restrict__ pofsC, const int* __restrict__ pofsR,
        int2* __restrict__ bufC, unsigned* __restrict__ bufR, int P, int E) {
    __shared__ int hc[512], hr[512];
    long o = (long)blockIdx.x * P;
    for (int i = threadIdx.x; i < P; i += 256) {
        hc[i] = pofsC[i] + cntC[o + i];
        hr[i] = pofsR[i] + cntR[o + i];
    }
    __syncthreads();
    int base = blockIdx.x * CHUNK;
    int lim = min(E, base + CHUNK);
    for (int e = base + threadIdx.x; e < lim; e += 256) {
        int r = row[e], c = col[e];
        float w = (r == c) ? 0.0f : ew[e];
        unsigned wb = __float_as_uint(w);
        int pc = atomicAdd(&hc[c >> 8], 1);
        bufC[pc] = make_int2((int)(((unsigned)(c & 255) << 24) | (unsigned)r), (int)wb);
        int pr = atomicAdd(&hr[r >> 8], 1);
        bufR[pr] = ((unsigned)(r & 255) << 24) | (wb >> 8);
    }
}

__global__ __launch_bounds__(256) void dinv_kernel(
        const unsigned* __restrict__ bufR, const int* __restrict__ rofs,
        float* __restrict__ dinv, int n) {
    int p = blockIdx.x;
    __shared__ float s[NPP];
    s[threadIdx.x] = 0.0f;
    __syncthreads();
    int beg = rofs[p], end = rofs[p + 1];
    for (int k = beg + threadIdx.x; k < end; k += 256) {
        unsigned u = bufR[k];
        atomicAdd(&s[u >> 24], __uint_as_float((u & 0xFFFFFFu) << 8));
    }
    __syncthreads();
    int node = (p << 8) + threadIdx.x;
    if (node < n) {
        float d = s[threadIdx.x];
        dinv[node] = d > 0.0f ? rsqrtf(d) : 0.0f;
    }
}

__global__ __launch_bounds__(256) void fine_csr_kernel(
        const int2* __restrict__ bufC, const int* __restrict__ pofs,
        const float* __restrict__ dinv, int* __restrict__ ofs,
        int2* __restrict__ epk, int n) {
    int p = blockIdx.x;
    int tid = threadIdx.x;
    __shared__ int hist[NPP];
    __shared__ int sc[NPP];
    __shared__ float dc[NPP];
    hist[tid] = 0;
    int node = (p << 8) + tid;
    dc[tid] = (node < n) ? dinv[node] : 0.0f;
    __syncthreads();
    int beg = pofs[p], end = pofs[p + 1];
    for (int k = beg + tid; k < end; k += 256)
        atomicAdd(&hist[((unsigned)bufC[k].x) >> 24], 1);
    __syncthreads();
    int v = hist[tid];
    sc[tid] = v;
    __syncthreads();
    for (int o = 1; o < 256; o <<= 1) {
        int t = (tid >= o) ? sc[tid - o] : 0;
        __syncthreads();
        sc[tid] += t;
        __syncthreads();
    }
    int mybase = beg + sc[tid] - v;  // exclusive
    if (node < n) ofs[node] = mybase;
    hist[tid] = mybase;  // becomes cursor
    __syncthreads();
    for (int k = beg + tid; k < end; k += 256) {
        int2 ed = bufC[k];
        unsigned key = (unsigned)ed.x;
        int fc = key >> 24;
        int r = (int)(key & 0xFFFFFFu);
        float w = __int_as_float(ed.y);
        float nrm = -dinv[r] * w * dc[fc];
        int pos = atomicAdd(&hist[fc], 1);
        epk[pos] = make_int2(r, __float_as_int(nrm));
    }
}

// ---------------- aggregation (bf16 gather, fp32 accumulate, bf16 out) ----------------

template <int D>
__global__ __launch_bounds__(256) void agg_kernel(
        const int* __restrict__ ofs, const int2* __restrict__ epk,
        const short* __restrict__ tb, short* __restrict__ outb, int n) {
    constexpr int LPN = D / 8;
    int idx = blockIdx.x * 256 + threadIdx.x;
    int node = idx / LPN;
    int l = idx % LPN;
    if (node >= n) return;
    int beg = ofs[node], end = ofs[node + 1];
    float a[8] = {0.f, 0.f, 0.f, 0.f, 0.f, 0.f, 0.f, 0.f};
    const short* tc = tb + l * 8;
    int k = beg;
    for (; k + 4 <= end; k += 4) {
        int2 ev[4];
        short8_t xv[4];
#pragma unroll
        for (int u = 0; u < 4; ++u) ev[u] = epk[k + u];
#pragma unroll
        for (int u = 0; u < 4; ++u)
            xv[u] = *reinterpret_cast<const short8_t*>(tc + (long)ev[u].x * D);
#pragma unroll
        for (int u = 0; u < 4; ++u) {
            float v = __int_as_float(ev[u].y);
#pragma unroll
            for (int j = 0; j < 8; ++j) a[j] = fmaf(v, bf2f(xv[u][j]), a[j]);
        }
    }
    for (; k < end; ++k) {
        int2 e0 = epk[k];
        short8_t x0 = *reinterpret_cast<const short8_t*>(tc + (long)e0.x * D);
        float v = __int_as_float(e0.y);
#pragma unroll
        for (int j = 0; j < 8; ++j) a[j] = fmaf(v, bf2f(x0[j]), a[j]);
    }
    short8_t s;
#pragma unroll
    for (int j = 0; j < 8; ++j) s[j] = f2bf(a[j]);
    *reinterpret_cast<short8_t*>(outb + (long)node * D + l * 8) = s;
}

// Dual agg for layer 3: tb [n][64] = [P1|P2] bf16; lanes 0-3 -> Q1b, 4-7 -> Q2b.

__global__ __launch_bounds__(256) void agg_dual_kernel(
        const int* __restrict__ ofs, const int2* __restrict__ epk,
        const short* __restrict__ tb, short* __restrict__ Q1b,
        short* __restrict__ Q2b, int n) {
    int idx = blockIdx.x * 256 + threadIdx.x;
    int node = idx >> 3;
    int l = idx & 7;
    if (node >= n) return;
    int beg = ofs[node], end = ofs[node + 1];
    float a[8] = {0.f, 0.f, 0.f, 0.f, 0.f, 0.f, 0.f, 0.f};
    const short* tc = tb + l * 8;
    int k = beg;
    for (; k + 4 <= end; k += 4) {
        int2 ev[4];
        short8_t xv[4];
#pragma unroll
        for (int u = 0; u < 4; ++u) ev[u] = epk[k + u];
#pragma unroll
        for (int u = 0; u < 4; ++u)
            xv[u] = *reinterpret_cast<const short8_t*>(tc + (long)ev[u].x * 64);
#pragma unroll
        for (int u = 0; u < 4; ++u) {
            float v = __int_as_float(ev[u].y);
#pragma unroll
            for (int j = 0; j < 8; ++j) a[j] = fmaf(v, bf2f(xv[u][j]), a[j]);
        }
    }
    for (; k < end; ++k) {
        int2 e0 = epk[k];
        short8_t x0 = *reinterpret_cast<const short8_t*>(tc + (long)e0.x * 64);
        float v = __int_as_float(e0.y);
#pragma unroll
        for (int j = 0; j < 8; ++j) a[j] = fmaf(v, bf2f(x0[j]), a[j]);
    }
    short* ob = (l < 4) ? Q1b : Q2b;
    long o = (long)node * 32 + (l & 3) * 8;
    short8_t s;
#pragma unroll
    for (int j = 0; j < 8; ++j) s[j] = f2bf(a[j]);
    *reinterpret_cast<short8_t*>(ob + o) = s;
}

// Final layer-3 agg: acc = L@Q2 gather; out = sigmoid(S + Q1 + 2*acc) (bf16).

__global__ __launch_bounds__(256) void agg_fin_kernel(
        const int* __restrict__ ofs, const int2* __restrict__ epk,
        const short* __restrict__ Q2b, const float* __restrict__ S,
        const short* __restrict__ Q1b, short* __restrict__ outb, int n) {
    int idx = blockIdx.x * 256 + threadIdx.x;
    int node = idx >> 2;
    int l = idx & 3;
    if (node >= n) return;
    int beg = ofs[node], end = ofs[node + 1];
    float a[8] = {0.f, 0.f, 0.f, 0.f, 0.f, 0.f, 0.f, 0.f};
    const short* tc = Q2b + l * 8;
    int k = beg;
    for (; k + 4 <= end; k += 4) {
        int2 ev[4];
        short8_t xv[4];
#pragma unroll
        for (int u = 0; u < 4; ++u) ev[u] = epk[k + u];
#pragma unroll
        for (int u = 0; u < 4; ++u)
            xv[u] = *reinterpret_cast<const short8_t*>(tc + (long)ev[u].x * 32);
#pragma unroll
        for (int u = 0; u < 4; ++u) {
            float v = __int_as_float(ev[u].y);
#pragma unroll
            for (int j = 0; j < 8; ++j) a[j] = fmaf(v, bf2f(xv[u][j]), a[j]);
        }
    }
    for (; k < end; ++k) {
        int2 e0 = epk[k];
        short8_t x0 = *reinterpret_cast<const short8_t*>(tc + (long)e0.x * 32);
        float v = __int_as_float(e0.y);
#pragma unroll
        for (int j = 0; j < 8; ++j) a[j] = fmaf(v, bf2f(x0[j]), a[j]);
    }
    long o = (long)node * 32 + l * 8;
    float4 s0 = *reinterpret_cast<const float4*>(S + o);
    float4 s1 = *reinterpret_cast<const float4*>(S + o + 4);
    short8_t q1 = *reinterpret_cast<const short8_t*>(Q1b + o);
    float sv[8] = {s0.x, s0.y, s0.z, s0.w, s1.x, s1.y, s1.z, s1.w};
    short8_t r;
#pragma unroll
    for (int j = 0; j < 8; ++j) {
        float z = sv[j] + bf2f(q1[j]) + 2.0f * a[j];
        r[j] = f2bf(1.0f / (1.0f + expf(-z)));
    }
    *reinterpret_cast<short8_t*>(outb + o) = r;
}

// ---------------- MFMA GEMMs ----------------
// out = sigmoid(t0@(W0-W2) + t1@W1 + U@(2*W2) + b), K=192, N=64.
// Block = 4 waves x 2 row-tiles of 16 = 128 rows. B frags held in VGPRs.

__global__ __launch_bounds__(256) void gemm3_mfma(
        const short* __restrict__ t0b, const short* __restrict__ t1b,
        const short* __restrict__ t2b, const short8_t* __restrict__ wpk,
        const float* __restrict__ b, short* __restrict__ outb, int n) {
    const int tid = threadIdx.x;
    const int wave = tid >> 6;
    const int lane = tid & 63;
    const int li = lane & 15;
    const int lg = lane >> 4;

    short8_t bfr[6][4];
#pragma unroll
    for (int s = 0; s < 6; ++s)
#pragma unroll
        for (int ct = 0; ct < 4; ++ct)
            bfr[s][ct] = wpk[(s * 4 + ct) * 64 + lane];

    float bias_v[4];
#pragma unroll
    for (int ct = 0; ct < 4; ++ct) bias_v[ct] = b[ct * 16 + li];

#pragma unroll
    for (int t = 0; t < 2; ++t) {
        int r0 = blockIdx.x * 128 + wave * 32 + t * 16;
        if (r0 >= n) continue;
        int rA = r0 + li;
        if (rA >= n) rA = n - 1;
        f32x4 acc[4] = {{0.f, 0.f, 0.f, 0.f}, {0.f, 0.f, 0.f, 0.f},
                        {0.f, 0.f, 0.f, 0.f}, {0.f, 0.f, 0.f, 0.f}};
#pragma unroll
        for (int s = 0; s < 6; ++s) {
            const short* src = (s < 2) ? t0b : (s < 4) ? t1b : t2b;
            int k = (s & 1) * 32 + lg * 8;
            short8_t a = *reinterpret_cast<const short8_t*>(src + (long)rA * 64 + k);
#pragma unroll
            for (int ct = 0; ct < 4; ++ct)
                acc[ct] = __builtin_amdgcn_mfma_f32_16x16x32_bf16(a, bfr[s][ct], acc[ct], 0, 0, 0);
        }
#pragma unroll
        for (int ct = 0; ct < 4; ++ct) {
#pragma unroll
            for (int reg = 0; reg < 4; ++reg) {
                int row = r0 + lg * 4 + reg;
                if (row < n) {
                    float z = acc[ct][reg] + bias_v[ct];
                    float res = 1.0f / (1.0f + expf(-z));
                    outb[(long)row * 64 + ct * 16 + li] = f2bf(res);
                }
            }
        }
    }
}

// Layer-3 multi GEMM: S = h@(W0-W2)+b (fp32), P12b = [h@W1 | h@W2] (bf16). K=64.

__global__ __launch_bounds__(256) void gemm_multi_mfma(
        const short* __restrict__ hb, const short8_t* __restrict__ wpk,
        const float* __restrict__ b, short* __restrict__ P12b,
        float* __restrict__ S, int n) {
    const int tid = threadIdx.x;
    const int wave = tid >> 6;
    const int lane = tid & 63;
    const int li = lane & 15;
    const int lg = lane >> 4;

    short8_t bfr[2][6];
#pragma unroll
    for (int s = 0; s < 2; ++s)
#pragma unroll
        for (int ct = 0; ct < 6; ++ct)
            bfr[s][ct] = wpk[(s * 6 + ct) * 64 + lane];

    float bS0 = b[li], bS1 = b[16 + li];

#pragma unroll
    for (int t = 0; t < 2; ++t) {
        int r0 = blockIdx.x * 128 + wave * 32 + t * 16;
        if (r0 >= n) continue;
        int rA = r0 + li;
        if (rA >= n) rA = n - 1;
        f32x4 acc[6] = {{0.f, 0.f, 0.f, 0.f}, {0.f, 0.f, 0.f, 0.f},
                        {0.f, 0.f, 0.f, 0.f}, {0.f, 0.f, 0.f, 0.f},
                        {0.f, 0.f, 0.f, 0.f}, {0.f, 0.f, 0.f, 0.f}};
#pragma unroll
        for (int s = 0; s < 2; ++s) {
            int k = s * 32 + lg * 8;
            short8_t a = *reinterpret_cast<const short8_t*>(hb + (long)rA * 64 + k);
#pragma unroll
            for (int ct = 0; ct < 6; ++ct)
                acc[ct] = __builtin_amdgcn_mfma_f32_16x16x32_bf16(a, bfr[s][ct], acc[ct], 0, 0, 0);
        }
#pragma unroll
        for (int ct = 0; ct < 6; ++ct) {
            int g = ct >> 1;
            int cl = (ct & 1) * 16 + li;
#pragma unroll
            for (int reg = 0; reg < 4; ++reg) {
                int row = r0 + lg * 4 + reg;
                if (row >= n) continue;
                float v = acc[ct][reg];
                if (g == 0) {
                    S[(long)row * 32 + cl] = v + ((ct & 1) ? bS1 : bS0);
                } else if (g == 1) {
                    P12b[(long)row * 64 + cl] = f2bf(v);
                } else {
                    P12b[(long)row * 64 + 32 + cl] = f2bf(v);
                }
            }
        }
    }
}

// Layer-4 GEMM: K=96 over 32-dim t0/t1/U, N=16, fp32 sigmoid out.

__global__ __launch_bounds__(256) void gemm4_mfma(
        const short* __restrict__ t0b, const short* __restrict__ t1b,
        const short* __restrict__ t2b, const short8_t* __restrict__ wpk,
        const float* __restrict__ b, float* __restrict__ out, int n) {
    const int tid = threadIdx.x;
    const int wave = tid >> 6;
    const int lane = tid & 63;
    const int li = lane & 15;
    const int lg = lane >> 4;

    short8_t bfr[3];
#pragma unroll
    for (int s = 0; s < 3; ++s) bfr[s] = wpk[s * 64 + lane];

    float bias_v = b[li];

#pragma unroll
    for (int t = 0; t < 2; ++t) {
        int r0 = blockIdx.x * 128 + wave * 32 + t * 16;
        if (r0 >= n) continue;
        int rA = r0 + li;
        if (rA >= n) rA = n - 1;
        f32x4 acc = {0.f, 0.f, 0.f, 0.f};
        int k = lg * 8;
        short8_t a0 = *reinterpret_cast<const short8_t*>(t0b + (long)rA * 32 + k);
        acc = __builtin_amdgcn_mfma_f32_16x16x32_bf16(a0, bfr[0], acc, 0, 0, 0);
        short8_t a1 = *reinterpret_cast<const short8_t*>(t1b + (long)rA * 32 + k);
        acc = __builtin_amdgcn_mfma_f32_16x16x32_bf16(a1, bfr[1], acc, 0, 0, 0);
        short8_t a2 = *reinterpret_cast<const short8_t*>(t2b + (long)rA * 32 + k);
        acc = __builtin_amdgcn_mfma_f32_16x16x32_bf16(a2, bfr[2], acc, 0, 0, 0);
#pragma unroll
        for (int reg = 0; reg < 4; ++reg) {
            int row = r0 + lg * 4 + reg;
            if (row < n) {
                float z = acc[reg] + bias_v;
                out[(long)row * 16 + li] = 1.0f / (1.0f + expf(-z));
            }
        }
    }
}

// ---------------- host side ----------------

static inline int ceil_div_l(long a, long b) { return (int)((a + b - 1) / b); }

extern "C" void kernel_launch(void* const* d_in, const int* in_sizes, int n_in,
                              void* d_out, int out_size, void* d_ws, size_t ws_size,
                              hipStream_t stream) {
    const float* x  = (const float*)d_in[0];
    const int*   ei = (const int*)d_in[1];
    const float* ew = (const float*)d_in[2];
    const float* W1 = (const float*)d_in[3];  const float* b1 = (const float*)d_in[4];
    const float* W2 = (const float*)d_in[5];  const float* b2 = (const float*)d_in[6];
    const float* W3 = (const float*)d_in[7];  const float* b3 = (const float*)d_in[8];
    const float* W4 = (const float*)d_in[9];  const float* b4 = (const float*)d_in[10];

    const int E = in_sizes[2];          // 1,600,000
    const int n = in_sizes[0] / 64;     // 100,000
    const int* row = ei;
    const int* col = ei + E;
    const int P = (n + NPP - 1) / NPP;  // 391 (<= 512)
    const int B = (E + CHUNK - 1) / CHUNK;  // 782

    // workspace carve-up (256B aligned)
    char* ws = (char*)d_ws;
    size_t off = 0;
    auto alloc = [&](size_t bytes) -> void* {
        void* p = ws + off;
        off += (bytes + 255) & ~(size_t)255;
        return p;
    };
    int*      cntC = (int*)alloc((size_t)B * P * sizeof(int));
    int*      cntR = (int*)alloc((size_t)B * P * sizeof(int));
    int*      ptotC = (int*)alloc(512 * sizeof(int));
    int*      ptotR = (int*)alloc(512 * sizeof(int));
    int*      pofsC = (int*)alloc((512 + 1) * sizeof(int));
    int*      pofsR = (int*)alloc((512 + 1) * sizeof(int));
    float*    dinv = (float*)alloc((size_t)n * sizeof(float));
    int*      ofs  = (int*)alloc((size_t)(n + 1) * sizeof(int));
    int2*     bufC = (int2*)alloc((size_t)E * sizeof(int2));
    unsigned* bufR = (unsigned*)alloc((size_t)E * sizeof(unsigned));
    int2*     epk  = (int2*)alloc((size_t)E * sizeof(int2));
    short*    hbA  = (short*)alloc((size_t)n * 64 * sizeof(short));
    short*    hbB  = (short*)alloc((size_t)n * 64 * sizeof(short));
    short*    t1b  = (short*)alloc((size_t)n * 64 * sizeof(short));
    short*    Ub   = (short*)alloc((size_t)n * 64 * sizeof(short));
    float*    S    = (float*)alloc((size_t)n * 32 * sizeof(float));
    short8_t* wpk1 = (short8_t*)alloc(1536 * sizeof(short8_t));
    short8_t* wpk2 = (short8_t*)alloc(1536 * sizeof(short8_t));
    short8_t* wpkm = (short8_t*)alloc(768 * sizeof(short8_t));
    short8_t* wpk4 = (short8_t*)alloc(192 * sizeof(short8_t));
    if (off > ws_size) return;  // fail loudly (validation) rather than corrupt

    // bf16 copy of x (layer-1 input) + weight fragment pre-pack
    f2b_kernel<<<ceil_div_l((long)n * 16, 256), 256, 0, stream>>>(x, hbA, (long)n * 64);
    prep_kernel<<<16, 256, 0, stream>>>(W1, W2, W3, W4, wpk1, wpk2, wpkm, wpk4);

    // CSR build: count -> colscan -> pscan -> scatter -> dinv -> fine (0 global atomics)
    count_kernel<<<B, 256, 0, stream>>>(row, col, cntC, cntR, P, E);
    colscan_kernel<<<2 * P, 256, 0, stream>>>(cntC, cntR, ptotC, ptotR, P, B);
    pscan_kernel<<<1, 512, 0, stream>>>(ptotC, ptotR, pofsC, pofsR, ofs, P, n, E);
    scatter_kernel<<<B, 256, 0, stream>>>(row, col, ew, cntC, cntR, pofsC, pofsR,
                                          bufC, bufR, P, E);
    dinv_kernel<<<P, 256, 0, stream>>>(bufR, pofsR, dinv, n);
    fine_csr_kernel<<<P, 256, 0, stream>>>(bufC, pofsC, dinv, ofs, epk, n);

    const int ab64 = ceil_div_l((long)n * 8, 256);
    const int ab32 = ceil_div_l((long)n * 4, 256);
    const int gb = ceil_div_l(n, 128);  // 782

    // Layer 1 (hbA = x): t1b = L@hbA; Ub = L@t1b; hbB = gemm
    agg_kernel<64><<<ab64, 256, 0, stream>>>(ofs, epk, hbA, t1b, n);
    agg_kernel<64><<<ab64, 256, 0, stream>>>(ofs, epk, t1b, Ub, n);
    gemm3_mfma<<<gb, 256, 0, stream>>>(hbA, t1b, Ub, wpk1, b1, hbB, n);

    // Layer 2: hbA = gemm(hbB, ...)
    agg_kernel<64><<<ab64, 256, 0, stream>>>(ofs, epk, hbB, t1b, n);
    agg_kernel<64><<<ab64, 256, 0, stream>>>(ofs, epk, t1b, Ub, n);
    gemm3_mfma<<<gb, 256, 0, stream>>>(hbB, t1b, Ub, wpk2, b2, hbA, n);

    // Layer 3 (64 -> 32), commute form, props in 32-dim:
    // P1=h@W1, P2=h@W2 (bf16 packed in t1b), S=h@(W0-W2)+b
    // out = sigma(S + L@P1 + 2*L@(L@P2))  -> hb3 = hbB[0:n*32]
    {
        short* P12b = t1b;
        short* Q1b  = Ub;
        short* Q2b  = Ub + (size_t)n * 32;
        short* hb3  = hbB;
        gemm_multi_mfma<<<gb, 256, 0, stream>>>(hbA, wpkm, b3, P12b, S, n);
        agg_dual_kernel<<<ab64, 256, 0, stream>>>(ofs, epk, P12b, Q1b, Q2b, n);
        agg_fin_kernel<<<ab32, 256, 0, stream>>>(ofs, epk, Q2b, S, Q1b, hb3, n);
    }

    // Layer 4 (32 -> 16): t1b32 = L@hb3; Ub32 = L@t1b32; d_out = gemm (fp32)
    agg_kernel<32><<<ab32, 256, 0, stream>>>(ofs, epk, hbB, t1b, n);
    agg_kernel<32><<<ab32, 256, 0, stream>>>(ofs, epk, t1b, Ub, n);
    gemm4_mfma<<<gb, 256, 0, stream>>>(hbB, t1b, Ub, wpk4, b4, (float*)d_out, n);
}